// Round 9
// baseline (11171.725 us; speedup 1.0000x reference)
//
#include <hip/hip_runtime.h>
#include <hip/hip_bf16.h>

#define BATCH 2048
#define LSIG 2048
#define TSTEPS 512
#define CH 8             // LSTM steps per chunk
#define NCHUNK (TSTEPS / CH)
#define SPB 2            // samples per block (one wave)

typedef float v2f __attribute__((ext_vector_type(2)));
typedef float v4f __attribute__((ext_vector_type(4)));

__device__ __forceinline__ void pk_fma(v2f& d, v2f a, v2f b) {
    // compiler-generated packed FMA (v_pk_fma_f32) — no inline-asm tie
    // constraints, so the allocator/scheduler keep full freedom (R9 test:
    // asm "+v" version suspected of v_mov copy bloat).
    d = __builtin_elementwise_fma(a, b, d);
}

__device__ __forceinline__ float sigf(float x) {
    return __fdividef(1.f, 1.f + __expf(-x));
}
__device__ __forceinline__ float tanhfast(float x) {
    return 1.f - __fdividef(2.f, __expf(2.f * x) + 1.f);
}

// One 64-lane wave per (2 samples, branch). R8 structure; only change vs R8:
// pk_fma implemented via __builtin_elementwise_fma instead of inline asm.
__global__ __launch_bounds__(64, 2) void branch_kernel(
    const float* __restrict__ x0, const float* __restrict__ x1,
    const float* __restrict__ x2, const float* __restrict__ x3,
    const float* __restrict__ c1w, const float* __restrict__ c1b,
    const float* __restrict__ c2w, const float* __restrict__ c2b,
    const float* __restrict__ wih, const float* __restrict__ whh,
    const float* __restrict__ bih, const float* __restrict__ bhh,
    float* __restrict__ feats)
{
    const int s0   = blockIdx.x * SPB;
    const int br   = blockIdx.y;
    const int lane = threadIdx.x;
    const float* xg = (br == 0) ? x0 : (br == 1) ? x1 : (br == 2) ? x2 : x3;

    __shared__ float xs_c[4 * CH + 6];        // x window (38)
    __shared__ float p1buf[2 * CH + 2][16];   // pooled1 window (18 rows)
    __shared__ float seqb[SPB][CH][32];       // conv2 outputs = LSTM inputs
    __shared__ float hb[2][SPB][32];          // double-buffered hidden state

    const int ci = lane & 15;         // conv1 out-channel
    const int co = lane & 31;         // conv2 out-channel
    const int hf = lane >> 5;         // conv2 input-channel half

    // LSTM biases for gate rows lane (i/f) and lane+64 (g/o)
    const float bs0 = bih[br * 128 + lane]      + bhh[br * 128 + lane];
    const float bs1 = bih[br * 128 + lane + 64] + bhh[br * 128 + lane + 64];

    hb[0][lane >> 5][lane & 31] = 0.f;        // zero hb[0][ss][*]
    float cst0 = 0.f, cst1 = 0.f;

    #pragma unroll 1
    for (int chk = 0; chk < NCHUNK; ++chk) {
        const int tc0 = chk * CH;

        // ---- conv weights: reload per chunk via opaque pointers ----
        const float* pc1 = c1w + br * 48 + ci * 3;  asm volatile("" : "+v"(pc1));
        const float w10 = pc1[0], w11 = pc1[1], w12 = pc1[2];
        const float* pb1 = c1b + br * 16 + ci;      asm volatile("" : "+v"(pb1));
        const float b1v = pb1[0];

        const float* pc2 = c2w + br * 1536 + co * 48 + hf * 24;
        asm volatile("" : "+v"(pc2));
        float wt[24];
        #pragma unroll
        for (int i = 0; i < 6; ++i) ((v4f*)wt)[i] = ((const v4f*)pc2)[i];
        v4f w2p[3][2];
        #pragma unroll
        for (int k = 0; k < 3; ++k)
            #pragma unroll
            for (int h2 = 0; h2 < 2; ++h2)
                w2p[k][h2] = (v4f){ wt[(h2 * 4 + 0) * 3 + k], wt[(h2 * 4 + 1) * 3 + k],
                                    wt[(h2 * 4 + 2) * 3 + k], wt[(h2 * 4 + 3) * 3 + k] };
        const float* pb2 = c2b + br * 32 + co;      asm volatile("" : "+v"(pb2));
        const float b2v = pb2[0];

        // ---- per-sample front-end: stage -> A -> B ----
        #pragma unroll 1
        for (int ss = 0; ss < SPB; ++ss) {
            __syncthreads();   // protect xs/p1buf/seqb from previous users
            if (lane < 4 * CH + 6) {
                int g = 4 * tc0 - 3 + lane;
                xs_c[lane] = ((unsigned)g < (unsigned)LSIG)
                           ? xg[(size_t)(s0 + ss) * LSIG + g] : 0.f;
            }
            __syncthreads();

            // phase A: (2CH+2) x 16 pooled1 window
            #pragma unroll
            for (int it = 0; it < 5; ++it) {
                int idx = it * 64 + lane;
                if (idx < (2 * CH + 2) * 16) {
                    int pl = idx >> 4;
                    float xa = xs_c[2 * pl + 0], xb = xs_c[2 * pl + 1];
                    float xc = xs_c[2 * pl + 2], xd = xs_c[2 * pl + 3];
                    float a0 = fmaf(xc, w12, fmaf(xb, w11, fmaf(xa, w10, b1v)));
                    float a1 = fmaf(xd, w12, fmaf(xc, w11, fmaf(xb, w10, b1v)));
                    float v = fmaxf(fmaxf(a0, a1), 0.f);
                    int p1g = 2 * tc0 - 1 + pl;
                    v = ((unsigned)p1g < (unsigned)(LSIG / 2)) ? v : 0.f;
                    p1buf[pl][idx & 15] = v;
                }
            }
            __syncthreads();

            // phase B: conv2 + relu + pool2 -> seqb[ss] (sliding row window)
            {
                const v4f* pbase = (const v4f*)&p1buf[0][0];   // 4 v4f per row
                const int h2o = hf * 2;
                v4f r0a = pbase[0 * 4 + h2o], r0b = pbase[0 * 4 + h2o + 1];
                v4f r1a = pbase[1 * 4 + h2o], r1b = pbase[1 * 4 + h2o + 1];
                v4f r2a = pbase[2 * 4 + h2o], r2b = pbase[2 * 4 + h2o + 1];
                v4f r3a = pbase[3 * 4 + h2o], r3b = pbase[3 * 4 + h2o + 1];
                #pragma unroll 1
                for (int tl = 0; tl < CH; ++tl) {
                    v2f aA = {0.f, 0.f}, aB = {0.f, 0.f};
                    pk_fma(aA, r0a.xy, w2p[0][0].xy); pk_fma(aA, r0a.zw, w2p[0][0].zw);
                    pk_fma(aA, r0b.xy, w2p[0][1].xy); pk_fma(aA, r0b.zw, w2p[0][1].zw);
                    pk_fma(aA, r1a.xy, w2p[1][0].xy); pk_fma(aA, r1a.zw, w2p[1][0].zw);
                    pk_fma(aA, r1b.xy, w2p[1][1].xy); pk_fma(aA, r1b.zw, w2p[1][1].zw);
                    pk_fma(aA, r2a.xy, w2p[2][0].xy); pk_fma(aA, r2a.zw, w2p[2][0].zw);
                    pk_fma(aA, r2b.xy, w2p[2][1].xy); pk_fma(aA, r2b.zw, w2p[2][1].zw);
                    pk_fma(aB, r1a.xy, w2p[0][0].xy); pk_fma(aB, r1a.zw, w2p[0][0].zw);
                    pk_fma(aB, r1b.xy, w2p[0][1].xy); pk_fma(aB, r1b.zw, w2p[0][1].zw);
                    pk_fma(aB, r2a.xy, w2p[1][0].xy); pk_fma(aB, r2a.zw, w2p[1][0].zw);
                    pk_fma(aB, r2b.xy, w2p[1][1].xy); pk_fma(aB, r2b.zw, w2p[1][1].zw);
                    pk_fma(aB, r3a.xy, w2p[2][0].xy); pk_fma(aB, r3a.zw, w2p[2][0].zw);
                    pk_fma(aB, r3b.xy, w2p[2][1].xy); pk_fma(aB, r3b.zw, w2p[2][1].zw);
                    float sA = aA.x + aA.y, sB = aB.x + aB.y;
                    sA += __shfl_xor(sA, 32);
                    sB += __shfl_xor(sB, 32);
                    if (hf == 0)
                        seqb[ss][tl][co] = fmaxf(fmaxf(sA, sB) + b2v, 0.f);
                    r0a = r2a; r0b = r2b; r1a = r3a; r1b = r3b;
                    if (tl < CH - 1) {
                        r2a = pbase[(2 * tl + 4) * 4 + h2o]; r2b = pbase[(2 * tl + 4) * 4 + h2o + 1];
                        r3a = pbase[(2 * tl + 5) * 4 + h2o]; r3b = pbase[(2 * tl + 5) * 4 + h2o + 1];
                    }
                }
            }
        }
        __syncthreads();

        // ---- phase B': x-part of gates, both samples -> 32 registers ----
        float gpx0[SPB][CH], gpx1[SPB][CH];
        {
            const float* pwi = wih + (size_t)br * 4096 + (size_t)lane * 32;
            asm volatile("" : "+v"(pwi));
            v4f wiA[8], wiB[8];
            #pragma unroll
            for (int j = 0; j < 8; ++j) {
                wiA[j] = ((const v4f*)pwi)[j];
                wiB[j] = ((const v4f*)(pwi + 64 * 32))[j];
            }
            #pragma unroll
            for (int ss = 0; ss < SPB; ++ss) {
                #pragma unroll
                for (int tl = 0; tl < CH; ++tl) {
                    const v4f* xq = (const v4f*)&seqb[ss][tl][0];
                    v2f aA = {0.f, 0.f}, aB = {0.f, 0.f};
                    #pragma unroll
                    for (int j = 0; j < 8; ++j) {
                        v4f xv = xq[j];
                        pk_fma(aA, xv.xy, wiA[j].xy); pk_fma(aA, xv.zw, wiA[j].zw);
                        pk_fma(aB, xv.xy, wiB[j].xy); pk_fma(aB, xv.zw, wiB[j].zw);
                    }
                    gpx0[ss][tl] = aA.x + aA.y;
                    gpx1[ss][tl] = aB.x + aB.y;
                }
            }
        }

        // ---- phase C: h-part, both samples interleaved per step ----
        {
            const float* pwh = whh + (size_t)br * 4096 + (size_t)lane * 32;
            asm volatile("" : "+v"(pwh));
            v4f whA[8], whB[8];
            #pragma unroll
            for (int j = 0; j < 8; ++j) {
                whA[j] = ((const v4f*)pwh)[j];
                whB[j] = ((const v4f*)(pwh + 64 * 32))[j];
            }
            #pragma unroll
            for (int tl = 0; tl < CH; ++tl) {
                __syncthreads();
                const int p = tl & 1;          // tc0 even => parity = tl&1
                const v4f* hq0 = (const v4f*)&hb[p][0][0];
                const v4f* hq1 = (const v4f*)&hb[p][1][0];
                v2f aA0 = {0.f, 0.f}, aB0 = {0.f, 0.f};
                v2f aA1 = {0.f, 0.f}, aB1 = {0.f, 0.f};
                #pragma unroll
                for (int j = 0; j < 8; ++j) {
                    v4f h0 = hq0[j];
                    v4f h1 = hq1[j];
                    pk_fma(aA0, h0.xy, whA[j].xy); pk_fma(aA0, h0.zw, whA[j].zw);
                    pk_fma(aB0, h0.xy, whB[j].xy); pk_fma(aB0, h0.zw, whB[j].zw);
                    pk_fma(aA1, h1.xy, whA[j].xy); pk_fma(aA1, h1.zw, whA[j].zw);
                    pk_fma(aB1, h1.xy, whB[j].xy); pk_fma(aB1, h1.zw, whB[j].zw);
                }
                // sample 0
                float g00 = bs0 + gpx0[0][tl] + aA0.x + aA0.y;
                float g10 = bs1 + gpx1[0][tl] + aB0.x + aB0.y;
                // sample 1
                float g01 = bs0 + gpx0[1][tl] + aA1.x + aA1.y;
                float g11 = bs1 + gpx1[1][tl] + aB1.x + aB1.y;

                float a00 = sigf(g00);
                float a01 = sigf(g01);
                float e0 = __expf(fminf((lane < 32) ? 2.f * g10 : -g10, 80.f));
                float e1 = __expf(fminf((lane < 32) ? 2.f * g11 : -g11, 80.f));
                float n0 = (lane < 32) ? e0 - 1.f : 1.f;
                float n1 = (lane < 32) ? e1 - 1.f : 1.f;
                float a10 = __fdividef(n0, e0 + 1.f);
                float a11 = __fdividef(n1, e1 + 1.f);
                float fa0 = __shfl_xor(a00, 32);
                float fa1 = __shfl_xor(a01, 32);
                float oa0 = __shfl_xor(a10, 32);
                float oa1 = __shfl_xor(a11, 32);
                if (lane < 32) {
                    cst0 = fmaf(fa0, cst0, a00 * a10);
                    cst1 = fmaf(fa1, cst1, a01 * a11);
                    hb[p ^ 1][0][lane] = oa0 * tanhfast(cst0);
                    hb[p ^ 1][1][lane] = oa1 * tanhfast(cst1);
                }
            }
        }
    }

    __syncthreads();
    // last step (t=511) wrote parity (7&1)^1 = 0
    feats[((size_t)br * BATCH + s0 + (lane >> 5)) * 32 + (lane & 31)] =
        hb[0][lane >> 5][lane & 31];
}

// ---------------- tail: bottleneck + 8-qubit statevector + classifier -------

__device__ __forceinline__ void apply1q(float2* psi, int lane, int q,
                                        float2 g00, float2 g01,
                                        float2 g10, float2 g11)
{
    const int shift = 7 - q;
    const int right = 1 << shift;
    #pragma unroll
    for (int pp = 0; pp < 2; ++pp) {
        int p  = lane + 64 * pp;
        int l  = p >> shift;
        int r  = p & (right - 1);
        int i0 = (l << (shift + 1)) + r;
        int i1 = i0 + right;
        float2 a = psi[i0], b = psi[i1];
        float2 n0 = make_float2(g00.x * a.x - g00.y * a.y + g01.x * b.x - g01.y * b.y,
                                g00.x * a.y + g00.y * a.x + g01.x * b.y + g01.y * b.x);
        float2 n1 = make_float2(g10.x * a.x - g10.y * a.y + g11.x * b.x - g11.y * b.y,
                                g10.x * a.y + g10.y * a.x + g11.x * b.y + g11.y * b.x);
        psi[i0] = n0;
        psi[i1] = n1;
    }
    __syncthreads();
}

__global__ __launch_bounds__(64) void tail_kernel(
    const float* __restrict__ feats, const float* __restrict__ bw,
    const float* __restrict__ bb, const float* __restrict__ qw,
    const float* __restrict__ cw, const float* __restrict__ cb,
    float* __restrict__ out)
{
    const int s    = blockIdx.x;
    const int lane = threadIdx.x;

    __shared__ float comb[128];
    __shared__ float2 psi[256];
    __shared__ float ang[8];

    comb[lane]      = feats[(size_t)(lane >> 5) * (BATCH * 32) + (size_t)s * 32 + (lane & 31)];
    comb[lane + 64] = feats[(size_t)((lane + 64) >> 5) * (BATCH * 32) + (size_t)s * 32 + (lane & 31)];
    __syncthreads();

    {
        int q = lane >> 3, k0 = lane & 7;
        float p = 0.f;
        #pragma unroll
        for (int i = 0; i < 16; ++i) {
            int k = k0 + 8 * i;
            p = fmaf(comb[k], bw[q * 128 + k], p);
        }
        p += __shfl_xor(p, 4);
        p += __shfl_xor(p, 2);
        p += __shfl_xor(p, 1);
        if (k0 == 0) ang[q] = tanhf(p + bb[q]);
    }
    #pragma unroll
    for (int r = 0; r < 4; ++r) {
        int idx = lane + 64 * r;
        psi[idx] = make_float2(idx == 0 ? 1.f : 0.f, 0.f);
    }
    __syncthreads();

    const float PI_F = 3.14159265358979323846f;

    for (int q = 0; q < 8; ++q) {
        float half = ang[q] * PI_F * 0.5f;
        float cv = cosf(half), sv = sinf(half);
        apply1q(psi, lane, q,
                make_float2(cv, 0.f), make_float2(0.f, -sv),
                make_float2(0.f, -sv), make_float2(cv, 0.f));
    }

    for (int l = 0; l < 3; ++l) {
        for (int q = 0; q < 8; ++q) {
            float phi = qw[(l * 8 + q) * 3 + 0];
            float th  = qw[(l * 8 + q) * 3 + 1];
            float om  = qw[(l * 8 + q) * 3 + 2];
            float ct = cosf(0.5f * th), st = sinf(0.5f * th);
            float A = 0.5f * (phi + om), D = 0.5f * (phi - om);
            float cA = cosf(A), sA = sinf(A), cD = cosf(D), sD = sinf(D);
            apply1q(psi, lane, q,
                    make_float2(ct * cA, -ct * sA), make_float2(-st * cD, -st * sD),
                    make_float2(st * cD, -st * sD), make_float2(ct * cA,  ct * sA));
        }
        int stride = l + 1;
        for (int q = 0; q + stride < 8; ++q) {
            int cbit = 1 << (7 - q);
            int tbit = 1 << (7 - (q + stride));
            #pragma unroll
            for (int r = 0; r < 4; ++r) {
                int idx = lane + 64 * r;
                if ((idx & cbit) && !(idx & tbit)) {
                    int j = idx | tbit;
                    float2 tmp = psi[idx];
                    psi[idx] = psi[j];
                    psi[j] = tmp;
                }
            }
            __syncthreads();
        }
    }

    float z[8];
    #pragma unroll
    for (int q = 0; q < 8; ++q) z[q] = 0.f;
    #pragma unroll
    for (int r = 0; r < 4; ++r) {
        int idx = lane + 64 * r;
        float2 a = psi[idx];
        float pr = a.x * a.x + a.y * a.y;
        #pragma unroll
        for (int q = 0; q < 8; ++q)
            z[q] += (idx & (1 << (7 - q))) ? -pr : pr;
    }
    #pragma unroll
    for (int q = 0; q < 8; ++q) {
        #pragma unroll
        for (int off = 32; off; off >>= 1) z[q] += __shfl_xor(z[q], off);
    }
    if (lane == 0) {
        #pragma unroll
        for (int c = 0; c < 3; ++c) {
            float acc = cb[c];
            #pragma unroll
            for (int q = 0; q < 8; ++q) acc = fmaf(z[q], cw[c * 8 + q], acc);
            out[s * 3 + c] = acc;
        }
    }
}

extern "C" void kernel_launch(void* const* d_in, const int* in_sizes, int n_in,
                              void* d_out, int out_size, void* d_ws, size_t ws_size,
                              hipStream_t stream)
{
    (void)in_sizes; (void)n_in; (void)out_size; (void)ws_size;
    const float* x0  = (const float*)d_in[0];
    const float* x1  = (const float*)d_in[1];
    const float* x2  = (const float*)d_in[2];
    const float* x3  = (const float*)d_in[3];
    const float* c1w = (const float*)d_in[4];
    const float* c1b = (const float*)d_in[5];
    const float* c2w = (const float*)d_in[6];
    const float* c2b = (const float*)d_in[7];
    const float* wih = (const float*)d_in[8];
    const float* whh = (const float*)d_in[9];
    const float* bih = (const float*)d_in[10];
    const float* bhh = (const float*)d_in[11];
    const float* bw  = (const float*)d_in[12];
    const float* bb  = (const float*)d_in[13];
    const float* qw  = (const float*)d_in[14];
    const float* cw  = (const float*)d_in[15];
    const float* cb  = (const float*)d_in[16];

    float* feats = (float*)d_ws;  // [4][BATCH][32] f32 = 1 MB

    branch_kernel<<<dim3(BATCH / SPB, 4), 64, 0, stream>>>(
        x0, x1, x2, x3, c1w, c1b, c2w, c2b, wih, whh, bih, bhh, feats);
    tail_kernel<<<BATCH, 64, 0, stream>>>(
        feats, bw, bb, qw, cw, cb, (float*)d_out);
}

// Round 10
// 8845.139 us; speedup vs baseline: 1.2630x; 1.2630x over previous
//
#include <hip/hip_runtime.h>
#include <hip/hip_bf16.h>

#define BATCH 2048
#define LSIG 2048
#define TSTEPS 512
#define CH 16            // LSTM steps per chunk
#define NCHUNK (TSTEPS / CH)

typedef float v2f __attribute__((ext_vector_type(2)));
typedef float v4f __attribute__((ext_vector_type(4)));

__device__ __forceinline__ void pk_fma(v2f& d, v2f a, v2f b) {
    // compiler-lowered packed FMA. R9 tested this with SPB=2 and spilled
    // (demand >128) -> confounded. R10: SPB=1 (demand ~110-120, fits 128).
    d = __builtin_elementwise_fma(a, b, d);
}

__device__ __forceinline__ float sigf(float x) {
    return __fdividef(1.f, 1.f + __expf(-x));
}
__device__ __forceinline__ float tanhfast(float x) {
    return 1.f - __fdividef(2.f, __expf(2.f * x) + 1.f);
}

// One 64-lane wave per (sample, branch). R7 structure, builtin pk_fma:
//  A : conv1+relu+pool2 -> p1buf[34][16]
//  B : conv2+relu+pool2 -> seqb[16][32]
//  B': x-part of LSTM gates -> gpx[16]x2 registers (Wih 64 regs, opaque reload)
//  C : h-part (Whh 64 regs) + activations, double-buffered h in LDS.
// EMPIRICAL model (R2-R9): VGPR budget = 256/arg2. arg2=2 -> 128.
__global__ __launch_bounds__(64, 2) void branch_kernel(
    const float* __restrict__ x0, const float* __restrict__ x1,
    const float* __restrict__ x2, const float* __restrict__ x3,
    const float* __restrict__ c1w, const float* __restrict__ c1b,
    const float* __restrict__ c2w, const float* __restrict__ c2b,
    const float* __restrict__ wih, const float* __restrict__ whh,
    const float* __restrict__ bih, const float* __restrict__ bhh,
    float* __restrict__ feats)
{
    const int s    = blockIdx.x;
    const int br   = blockIdx.y;
    const int lane = threadIdx.x;
    const float* xg = (br == 0) ? x0 : (br == 1) ? x1 : (br == 2) ? x2 : x3;

    __shared__ float xs_c[70];        // x window for one chunk
    __shared__ float p1buf[34][16];   // pooled1 window
    __shared__ float seqb[CH][32];    // conv2 outputs = LSTM inputs
    __shared__ float hb[2][32];       // double-buffered hidden state

    const int ci = lane & 15;         // conv1 out-channel
    const int co = lane & 31;         // conv2 out-channel
    const int hf = lane >> 5;         // conv2 input-channel half

    // LSTM biases for gate rows lane (i/f) and lane+64 (g/o)
    const float bs0 = bih[br * 128 + lane]      + bhh[br * 128 + lane];
    const float bs1 = bih[br * 128 + lane + 64] + bhh[br * 128 + lane + 64];

    if (lane < 32) hb[0][lane] = 0.f;
    float c_state = 0.f;

    #pragma unroll 1
    for (int chk = 0; chk < NCHUNK; ++chk) {
        const int tc0 = chk * CH;

        // ---- stage x window: xs_c[i] = x[4*tc0 - 3 + i], i<70 ----
        {
            int g = 4 * tc0 - 3 + lane;
            xs_c[lane] = ((unsigned)g < (unsigned)LSIG) ? xg[(size_t)s * LSIG + g] : 0.f;
            if (lane < 6) {
                int g2 = 4 * tc0 + 61 + lane;
                xs_c[64 + lane] = ((unsigned)g2 < (unsigned)LSIG) ? xg[(size_t)s * LSIG + g2] : 0.f;
            }
        }

        // ---- conv weights: reload per chunk via opaque pointers ----
        const float* pc1 = c1w + br * 48 + ci * 3;  asm volatile("" : "+v"(pc1));
        const float w10 = pc1[0], w11 = pc1[1], w12 = pc1[2];
        const float* pb1 = c1b + br * 16 + ci;      asm volatile("" : "+v"(pb1));
        const float b1v = pb1[0];

        const float* pc2 = c2w + br * 1536 + co * 48 + hf * 24;
        asm volatile("" : "+v"(pc2));
        float wt[24];
        #pragma unroll
        for (int i = 0; i < 6; ++i) ((v4f*)wt)[i] = ((const v4f*)pc2)[i];
        v4f w2p[3][2];
        #pragma unroll
        for (int k = 0; k < 3; ++k)
            #pragma unroll
            for (int h2 = 0; h2 < 2; ++h2)
                w2p[k][h2] = (v4f){ wt[(h2 * 4 + 0) * 3 + k], wt[(h2 * 4 + 1) * 3 + k],
                                    wt[(h2 * 4 + 2) * 3 + k], wt[(h2 * 4 + 3) * 3 + k] };
        const float* pb2 = c2b + br * 32 + co;      asm volatile("" : "+v"(pb2));
        const float b2v = pb2[0];

        __syncthreads();

        // ---- phase A: 34 x 16 pooled1 window ----
        #pragma unroll 1
        for (int it = 0; it < 9; ++it) {
            int idx = it * 64 + lane;
            if (idx < 34 * 16) {
                int pl = idx >> 4;
                float xa = xs_c[2 * pl + 0], xb = xs_c[2 * pl + 1];
                float xc = xs_c[2 * pl + 2], xd = xs_c[2 * pl + 3];
                float a0 = fmaf(xc, w12, fmaf(xb, w11, fmaf(xa, w10, b1v)));
                float a1 = fmaf(xd, w12, fmaf(xc, w11, fmaf(xb, w10, b1v)));
                float v = fmaxf(fmaxf(a0, a1), 0.f);
                int p1g = 2 * tc0 - 1 + pl;
                v = ((unsigned)p1g < (unsigned)(LSIG / 2)) ? v : 0.f;
                p1buf[pl][idx & 15] = v;
            }
        }
        __syncthreads();

        // ---- phase B: conv2 + relu + pool2 -> seqb (sliding row window) ----
        {
            const v4f* pbase = (const v4f*)&p1buf[0][0];   // 4 v4f per row
            const int h2o = hf * 2;
            v4f r0a = pbase[0 * 4 + h2o], r0b = pbase[0 * 4 + h2o + 1];
            v4f r1a = pbase[1 * 4 + h2o], r1b = pbase[1 * 4 + h2o + 1];
            v4f r2a = pbase[2 * 4 + h2o], r2b = pbase[2 * 4 + h2o + 1];
            v4f r3a = pbase[3 * 4 + h2o], r3b = pbase[3 * 4 + h2o + 1];
            #pragma unroll 1
            for (int tl = 0; tl < CH; ++tl) {
                v2f aA = {0.f, 0.f}, aB = {0.f, 0.f};
                pk_fma(aA, r0a.xy, w2p[0][0].xy); pk_fma(aA, r0a.zw, w2p[0][0].zw);
                pk_fma(aA, r0b.xy, w2p[0][1].xy); pk_fma(aA, r0b.zw, w2p[0][1].zw);
                pk_fma(aA, r1a.xy, w2p[1][0].xy); pk_fma(aA, r1a.zw, w2p[1][0].zw);
                pk_fma(aA, r1b.xy, w2p[1][1].xy); pk_fma(aA, r1b.zw, w2p[1][1].zw);
                pk_fma(aA, r2a.xy, w2p[2][0].xy); pk_fma(aA, r2a.zw, w2p[2][0].zw);
                pk_fma(aA, r2b.xy, w2p[2][1].xy); pk_fma(aA, r2b.zw, w2p[2][1].zw);
                pk_fma(aB, r1a.xy, w2p[0][0].xy); pk_fma(aB, r1a.zw, w2p[0][0].zw);
                pk_fma(aB, r1b.xy, w2p[0][1].xy); pk_fma(aB, r1b.zw, w2p[0][1].zw);
                pk_fma(aB, r2a.xy, w2p[1][0].xy); pk_fma(aB, r2a.zw, w2p[1][0].zw);
                pk_fma(aB, r2b.xy, w2p[1][1].xy); pk_fma(aB, r2b.zw, w2p[1][1].zw);
                pk_fma(aB, r3a.xy, w2p[2][0].xy); pk_fma(aB, r3a.zw, w2p[2][0].zw);
                pk_fma(aB, r3b.xy, w2p[2][1].xy); pk_fma(aB, r3b.zw, w2p[2][1].zw);
                float sA = aA.x + aA.y, sB = aB.x + aB.y;
                sA += __shfl_xor(sA, 32);
                sB += __shfl_xor(sB, 32);
                if (hf == 0)
                    seqb[tl][co] = fmaxf(fmaxf(sA, sB) + b2v, 0.f);
                r0a = r2a; r0b = r2b; r1a = r3a; r1b = r3b;
                if (tl < CH - 1) {
                    r2a = pbase[(2 * tl + 4) * 4 + h2o]; r2b = pbase[(2 * tl + 4) * 4 + h2o + 1];
                    r3a = pbase[(2 * tl + 5) * 4 + h2o]; r3b = pbase[(2 * tl + 5) * 4 + h2o + 1];
                }
            }
        }
        __syncthreads();

        // ---- phase B': x-part of gates for the whole chunk -> registers ----
        float gpx0[CH], gpx1[CH];
        {
            const float* pwi = wih + (size_t)br * 4096 + (size_t)lane * 32;
            asm volatile("" : "+v"(pwi));
            v4f wiA[8], wiB[8];
            #pragma unroll
            for (int j = 0; j < 8; ++j) {
                wiA[j] = ((const v4f*)pwi)[j];
                wiB[j] = ((const v4f*)(pwi + 64 * 32))[j];
            }
            #pragma unroll
            for (int tl = 0; tl < CH; ++tl) {
                const v4f* xq = (const v4f*)&seqb[tl][0];
                v2f aA = {0.f, 0.f}, aB = {0.f, 0.f};
                #pragma unroll
                for (int j = 0; j < 8; ++j) {
                    v4f xv = xq[j];
                    pk_fma(aA, xv.xy, wiA[j].xy); pk_fma(aA, xv.zw, wiA[j].zw);
                    pk_fma(aB, xv.xy, wiB[j].xy); pk_fma(aB, xv.zw, wiB[j].zw);
                }
                gpx0[tl] = aA.x + aA.y;
                gpx1[tl] = aB.x + aB.y;
            }
        }

        // ---- phase C: recurrent h-part, one (cheap) barrier per step ----
        {
            const float* pwh = whh + (size_t)br * 4096 + (size_t)lane * 32;
            asm volatile("" : "+v"(pwh));
            v4f whA[8], whB[8];
            #pragma unroll
            for (int j = 0; j < 8; ++j) {
                whA[j] = ((const v4f*)pwh)[j];
                whB[j] = ((const v4f*)(pwh + 64 * 32))[j];
            }
            #pragma unroll
            for (int tl = 0; tl < CH; ++tl) {
                __syncthreads();
                const int p = (tc0 + tl) & 1;
                const v4f* hq = (const v4f*)&hb[p][0];
                v2f aA = {0.f, 0.f}, aB = {0.f, 0.f};
                #pragma unroll
                for (int j = 0; j < 8; ++j) {
                    v4f hv = hq[j];
                    pk_fma(aA, hv.xy, whA[j].xy); pk_fma(aA, hv.zw, whA[j].zw);
                    pk_fma(aB, hv.xy, whB[j].xy); pk_fma(aB, hv.zw, whB[j].zw);
                }
                float g0 = bs0 + gpx0[tl] + aA.x + aA.y;  // i (lane<32) / f
                float g1 = bs1 + gpx1[tl] + aB.x + aB.y;  // g (lane<32) / o
                float a0 = sigf(g0);
                // tanh(g1) for lanes<32, sigmoid(g1) for lanes>=32 (shared exp)
                float earg = (lane < 32) ? 2.f * g1 : -g1;
                float e1 = __expf(fminf(earg, 80.f));
                float num = (lane < 32) ? e1 - 1.f : 1.f;
                float a1 = __fdividef(num, e1 + 1.f);
                float fa = __shfl_xor(a0, 32);   // sig(f_m) for lanes<32
                float oa = __shfl_xor(a1, 32);   // sig(o_m) for lanes<32
                if (lane < 32) {
                    c_state = fmaf(fa, c_state, a0 * a1);
                    hb[p ^ 1][lane] = oa * tanhfast(c_state);
                }
            }
        }
    }

    __syncthreads();
    // last step (t=511) wrote parity (511&1)^1 = 0
    if (lane < 32)
        feats[((size_t)br * BATCH + s) * 32 + lane] = hb[0][lane];
}

// ---------------- tail: bottleneck + 8-qubit statevector + classifier -------

__device__ __forceinline__ void apply1q(float2* psi, int lane, int q,
                                        float2 g00, float2 g01,
                                        float2 g10, float2 g11)
{
    const int shift = 7 - q;
    const int right = 1 << shift;
    #pragma unroll
    for (int pp = 0; pp < 2; ++pp) {
        int p  = lane + 64 * pp;
        int l  = p >> shift;
        int r  = p & (right - 1);
        int i0 = (l << (shift + 1)) + r;
        int i1 = i0 + right;
        float2 a = psi[i0], b = psi[i1];
        float2 n0 = make_float2(g00.x * a.x - g00.y * a.y + g01.x * b.x - g01.y * b.y,
                                g00.x * a.y + g00.y * a.x + g01.x * b.y + g01.y * b.x);
        float2 n1 = make_float2(g10.x * a.x - g10.y * a.y + g11.x * b.x - g11.y * b.y,
                                g10.x * a.y + g10.y * a.x + g11.x * b.y + g11.y * b.x);
        psi[i0] = n0;
        psi[i1] = n1;
    }
    __syncthreads();
}

__global__ __launch_bounds__(64) void tail_kernel(
    const float* __restrict__ feats, const float* __restrict__ bw,
    const float* __restrict__ bb, const float* __restrict__ qw,
    const float* __restrict__ cw, const float* __restrict__ cb,
    float* __restrict__ out)
{
    const int s    = blockIdx.x;
    const int lane = threadIdx.x;

    __shared__ float comb[128];
    __shared__ float2 psi[256];
    __shared__ float ang[8];

    comb[lane]      = feats[(size_t)(lane >> 5) * (BATCH * 32) + (size_t)s * 32 + (lane & 31)];
    comb[lane + 64] = feats[(size_t)((lane + 64) >> 5) * (BATCH * 32) + (size_t)s * 32 + (lane & 31)];
    __syncthreads();

    {
        int q = lane >> 3, k0 = lane & 7;
        float p = 0.f;
        #pragma unroll
        for (int i = 0; i < 16; ++i) {
            int k = k0 + 8 * i;
            p = fmaf(comb[k], bw[q * 128 + k], p);
        }
        p += __shfl_xor(p, 4);
        p += __shfl_xor(p, 2);
        p += __shfl_xor(p, 1);
        if (k0 == 0) ang[q] = tanhf(p + bb[q]);
    }
    #pragma unroll
    for (int r = 0; r < 4; ++r) {
        int idx = lane + 64 * r;
        psi[idx] = make_float2(idx == 0 ? 1.f : 0.f, 0.f);
    }
    __syncthreads();

    const float PI_F = 3.14159265358979323846f;

    for (int q = 0; q < 8; ++q) {
        float half = ang[q] * PI_F * 0.5f;
        float cv = cosf(half), sv = sinf(half);
        apply1q(psi, lane, q,
                make_float2(cv, 0.f), make_float2(0.f, -sv),
                make_float2(0.f, -sv), make_float2(cv, 0.f));
    }

    for (int l = 0; l < 3; ++l) {
        for (int q = 0; q < 8; ++q) {
            float phi = qw[(l * 8 + q) * 3 + 0];
            float th  = qw[(l * 8 + q) * 3 + 1];
            float om  = qw[(l * 8 + q) * 3 + 2];
            float ct = cosf(0.5f * th), st = sinf(0.5f * th);
            float A = 0.5f * (phi + om), D = 0.5f * (phi - om);
            float cA = cosf(A), sA = sinf(A), cD = cosf(D), sD = sinf(D);
            apply1q(psi, lane, q,
                    make_float2(ct * cA, -ct * sA), make_float2(-st * cD, -st * sD),
                    make_float2(st * cD, -st * sD), make_float2(ct * cA,  ct * sA));
        }
        int stride = l + 1;
        for (int q = 0; q + stride < 8; ++q) {
            int cbit = 1 << (7 - q);
            int tbit = 1 << (7 - (q + stride));
            #pragma unroll
            for (int r = 0; r < 4; ++r) {
                int idx = lane + 64 * r;
                if ((idx & cbit) && !(idx & tbit)) {
                    int j = idx | tbit;
                    float2 tmp = psi[idx];
                    psi[idx] = psi[j];
                    psi[j] = tmp;
                }
            }
            __syncthreads();
        }
    }

    float z[8];
    #pragma unroll
    for (int q = 0; q < 8; ++q) z[q] = 0.f;
    #pragma unroll
    for (int r = 0; r < 4; ++r) {
        int idx = lane + 64 * r;
        float2 a = psi[idx];
        float pr = a.x * a.x + a.y * a.y;
        #pragma unroll
        for (int q = 0; q < 8; ++q)
            z[q] += (idx & (1 << (7 - q))) ? -pr : pr;
    }
    #pragma unroll
    for (int q = 0; q < 8; ++q) {
        #pragma unroll
        for (int off = 32; off; off >>= 1) z[q] += __shfl_xor(z[q], off);
    }
    if (lane == 0) {
        #pragma unroll
        for (int c = 0; c < 3; ++c) {
            float acc = cb[c];
            #pragma unroll
            for (int q = 0; q < 8; ++q) acc = fmaf(z[q], cw[c * 8 + q], acc);
            out[s * 3 + c] = acc;
        }
    }
}

extern "C" void kernel_launch(void* const* d_in, const int* in_sizes, int n_in,
                              void* d_out, int out_size, void* d_ws, size_t ws_size,
                              hipStream_t stream)
{
    (void)in_sizes; (void)n_in; (void)out_size; (void)ws_size;
    const float* x0  = (const float*)d_in[0];
    const float* x1  = (const float*)d_in[1];
    const float* x2  = (const float*)d_in[2];
    const float* x3  = (const float*)d_in[3];
    const float* c1w = (const float*)d_in[4];
    const float* c1b = (const float*)d_in[5];
    const float* c2w = (const float*)d_in[6];
    const float* c2b = (const float*)d_in[7];
    const float* wih = (const float*)d_in[8];
    const float* whh = (const float*)d_in[9];
    const float* bih = (const float*)d_in[10];
    const float* bhh = (const float*)d_in[11];
    const float* bw  = (const float*)d_in[12];
    const float* bb  = (const float*)d_in[13];
    const float* qw  = (const float*)d_in[14];
    const float* cw  = (const float*)d_in[15];
    const float* cb  = (const float*)d_in[16];

    float* feats = (float*)d_ws;  // [4][BATCH][32] f32 = 1 MB

    branch_kernel<<<dim3(BATCH, 4), 64, 0, stream>>>(
        x0, x1, x2, x3, c1w, c1b, c2w, c2b, wih, whh, bih, bhh, feats);
    tail_kernel<<<BATCH, 64, 0, stream>>>(
        feats, bw, bb, qw, cw, cb, (float*)d_out);
}

// Round 11
// 2205.238 us; speedup vs baseline: 5.0660x; 4.0110x over previous
//
#include <hip/hip_runtime.h>
#include <hip/hip_bf16.h>

#define BATCH 2048
#define LSIG 2048
#define TSTEPS 512
#define CH 16
#define NCHUNK (TSTEPS / CH)

typedef float v2f __attribute__((ext_vector_type(2)));
typedef float v4f __attribute__((ext_vector_type(4)));
typedef __bf16 b16x8 __attribute__((ext_vector_type(8)));
typedef float f32x4 __attribute__((ext_vector_type(4)));

#define SEQ_ELEMS (4ULL * 512ULL * 2048ULL * 32ULL)          // 134217728
#define WS_NEED (2ULL * SEQ_ELEMS * 2ULL + 4ULL * 2048ULL * 32ULL * 4ULL)

__device__ __forceinline__ float sigf(float x) {
    return __fdividef(1.f, 1.f + __expf(-x));
}
__device__ __forceinline__ float tanhfast(float x) {
    return 1.f - __fdividef(2.f, __expf(2.f * x) + 1.f);
}
__device__ __forceinline__ unsigned short bf16rne(float f) {
    unsigned u = __float_as_uint(f);
    return (unsigned short)((u + 0x7FFFu + ((u >> 16) & 1u)) >> 16);
}
// swizzled channel position so K2 lane q reads 16B-contiguous frag halves:
// frag elems j0..3 = ch {4q+j}, j4..7 = ch {16+4q+j}
__device__ __forceinline__ int swz(int co) {
    return (co < 16) ? ((co >> 2) * 8 + (co & 3))
                     : (((co >> 2) - 4) * 8 + 4 + (co & 3));
}

// ============ K1: conv front-end -> seq hi/lo bf16 planes ==================
// one wave per (sample, branch, chunk-group of 8); phases A+B from R7.
__global__ __launch_bounds__(64) void frontend_kernel(
    const float* __restrict__ x0, const float* __restrict__ x1,
    const float* __restrict__ x2, const float* __restrict__ x3,
    const float* __restrict__ c1w, const float* __restrict__ c1b,
    const float* __restrict__ c2w, const float* __restrict__ c2b,
    unsigned short* __restrict__ seqh, unsigned short* __restrict__ seql)
{
    const int s    = blockIdx.x;
    const int br   = blockIdx.y & 3;
    const int cg   = blockIdx.y >> 2;
    const int lane = threadIdx.x;
    const float* xg = (br == 0) ? x0 : (br == 1) ? x1 : (br == 2) ? x2 : x3;

    __shared__ float xs_c[70];
    __shared__ float p1buf[34][16];

    const int ci = lane & 15;
    const int co = lane & 31;
    const int hf = lane >> 5;
    const int sp = swz(co);

    const float w10 = c1w[br * 48 + ci * 3 + 0];
    const float w11 = c1w[br * 48 + ci * 3 + 1];
    const float w12 = c1w[br * 48 + ci * 3 + 2];
    const float b1v = c1b[br * 16 + ci];

    float wt[24];
    {
        const v4f* p = (const v4f*)(c2w + br * 1536 + co * 48 + hf * 24);
        #pragma unroll
        for (int i = 0; i < 6; ++i) ((v4f*)wt)[i] = p[i];
    }
    v4f w2p[3][2];
    #pragma unroll
    for (int k = 0; k < 3; ++k)
        #pragma unroll
        for (int h2 = 0; h2 < 2; ++h2)
            w2p[k][h2] = (v4f){ wt[(h2 * 4 + 0) * 3 + k], wt[(h2 * 4 + 1) * 3 + k],
                                wt[(h2 * 4 + 2) * 3 + k], wt[(h2 * 4 + 3) * 3 + k] };
    const float b2v = c2b[br * 32 + co];

    #pragma unroll 1
    for (int ic = 0; ic < 8; ++ic) {
        const int chk = cg * 8 + ic;
        const int tc0 = chk * CH;

        __syncthreads();
        {
            int g = 4 * tc0 - 3 + lane;
            xs_c[lane] = ((unsigned)g < (unsigned)LSIG) ? xg[(size_t)s * LSIG + g] : 0.f;
            if (lane < 6) {
                int g2 = 4 * tc0 + 61 + lane;
                xs_c[64 + lane] = ((unsigned)g2 < (unsigned)LSIG) ? xg[(size_t)s * LSIG + g2] : 0.f;
            }
        }
        __syncthreads();

        // phase A
        #pragma unroll 1
        for (int it = 0; it < 9; ++it) {
            int idx = it * 64 + lane;
            if (idx < 34 * 16) {
                int pl = idx >> 4;
                float xa = xs_c[2 * pl + 0], xb = xs_c[2 * pl + 1];
                float xc = xs_c[2 * pl + 2], xd = xs_c[2 * pl + 3];
                float a0 = fmaf(xc, w12, fmaf(xb, w11, fmaf(xa, w10, b1v)));
                float a1 = fmaf(xd, w12, fmaf(xc, w11, fmaf(xb, w10, b1v)));
                float v = fmaxf(fmaxf(a0, a1), 0.f);
                int p1g = 2 * tc0 - 1 + pl;
                v = ((unsigned)p1g < (unsigned)(LSIG / 2)) ? v : 0.f;
                p1buf[pl][idx & 15] = v;
            }
        }
        __syncthreads();

        // phase B -> global seq hi/lo (swizzled channel layout)
        {
            const v4f* pbase = (const v4f*)&p1buf[0][0];
            const int h2o = hf * 2;
            v4f r0a = pbase[0 * 4 + h2o], r0b = pbase[0 * 4 + h2o + 1];
            v4f r1a = pbase[1 * 4 + h2o], r1b = pbase[1 * 4 + h2o + 1];
            v4f r2a = pbase[2 * 4 + h2o], r2b = pbase[2 * 4 + h2o + 1];
            v4f r3a = pbase[3 * 4 + h2o], r3b = pbase[3 * 4 + h2o + 1];
            #pragma unroll 1
            for (int tl = 0; tl < CH; ++tl) {
                v2f aA = {0.f, 0.f}, aB = {0.f, 0.f};
                asm("v_pk_fma_f32 %0, %1, %2, %0" : "+v"(aA) : "v"(r0a.xy), "v"(w2p[0][0].xy));
                asm("v_pk_fma_f32 %0, %1, %2, %0" : "+v"(aA) : "v"(r0a.zw), "v"(w2p[0][0].zw));
                asm("v_pk_fma_f32 %0, %1, %2, %0" : "+v"(aA) : "v"(r0b.xy), "v"(w2p[0][1].xy));
                asm("v_pk_fma_f32 %0, %1, %2, %0" : "+v"(aA) : "v"(r0b.zw), "v"(w2p[0][1].zw));
                asm("v_pk_fma_f32 %0, %1, %2, %0" : "+v"(aA) : "v"(r1a.xy), "v"(w2p[1][0].xy));
                asm("v_pk_fma_f32 %0, %1, %2, %0" : "+v"(aA) : "v"(r1a.zw), "v"(w2p[1][0].zw));
                asm("v_pk_fma_f32 %0, %1, %2, %0" : "+v"(aA) : "v"(r1b.xy), "v"(w2p[1][1].xy));
                asm("v_pk_fma_f32 %0, %1, %2, %0" : "+v"(aA) : "v"(r1b.zw), "v"(w2p[1][1].zw));
                asm("v_pk_fma_f32 %0, %1, %2, %0" : "+v"(aA) : "v"(r2a.xy), "v"(w2p[2][0].xy));
                asm("v_pk_fma_f32 %0, %1, %2, %0" : "+v"(aA) : "v"(r2a.zw), "v"(w2p[2][0].zw));
                asm("v_pk_fma_f32 %0, %1, %2, %0" : "+v"(aA) : "v"(r2b.xy), "v"(w2p[2][1].xy));
                asm("v_pk_fma_f32 %0, %1, %2, %0" : "+v"(aA) : "v"(r2b.zw), "v"(w2p[2][1].zw));
                asm("v_pk_fma_f32 %0, %1, %2, %0" : "+v"(aB) : "v"(r1a.xy), "v"(w2p[0][0].xy));
                asm("v_pk_fma_f32 %0, %1, %2, %0" : "+v"(aB) : "v"(r1a.zw), "v"(w2p[0][0].zw));
                asm("v_pk_fma_f32 %0, %1, %2, %0" : "+v"(aB) : "v"(r1b.xy), "v"(w2p[0][1].xy));
                asm("v_pk_fma_f32 %0, %1, %2, %0" : "+v"(aB) : "v"(r1b.zw), "v"(w2p[0][1].zw));
                asm("v_pk_fma_f32 %0, %1, %2, %0" : "+v"(aB) : "v"(r2a.xy), "v"(w2p[1][0].xy));
                asm("v_pk_fma_f32 %0, %1, %2, %0" : "+v"(aB) : "v"(r2a.zw), "v"(w2p[1][0].zw));
                asm("v_pk_fma_f32 %0, %1, %2, %0" : "+v"(aB) : "v"(r2b.xy), "v"(w2p[1][1].xy));
                asm("v_pk_fma_f32 %0, %1, %2, %0" : "+v"(aB) : "v"(r2b.zw), "v"(w2p[1][1].zw));
                asm("v_pk_fma_f32 %0, %1, %2, %0" : "+v"(aB) : "v"(r3a.xy), "v"(w2p[2][0].xy));
                asm("v_pk_fma_f32 %0, %1, %2, %0" : "+v"(aB) : "v"(r3a.zw), "v"(w2p[2][0].zw));
                asm("v_pk_fma_f32 %0, %1, %2, %0" : "+v"(aB) : "v"(r3b.xy), "v"(w2p[2][1].xy));
                asm("v_pk_fma_f32 %0, %1, %2, %0" : "+v"(aB) : "v"(r3b.zw), "v"(w2p[2][1].zw));
                float sA = aA.x + aA.y, sB = aB.x + aB.y;
                sA += __shfl_xor(sA, 32);
                sB += __shfl_xor(sB, 32);
                float sv = fmaxf(fmaxf(sA, sB) + b2v, 0.f);
                // hi/lo bf16 split
                unsigned short hb = bf16rne(sv);
                float hif = __uint_as_float(((unsigned)hb) << 16);
                unsigned short lb = bf16rne(sv - hif);
                size_t off = (((size_t)br * 512 + (tc0 + tl)) * 2048 + s) * 32 + sp;
                if (hf == 0) seqh[off] = hb;
                else         seql[off] = lb;
                r0a = r2a; r0b = r2b; r1a = r3a; r1b = r3b;
                if (tl < CH - 1) {
                    r2a = pbase[(2 * tl + 4) * 4 + h2o]; r2b = pbase[(2 * tl + 4) * 4 + h2o + 1];
                    r3a = pbase[(2 * tl + 5) * 4 + h2o]; r3b = pbase[(2 * tl + 5) * 4 + h2o + 1];
                }
            }
        }
    }
}

// ============ K2: MFMA LSTM, 16 samples per wave ===========================
// D[gates x samples] = Whh[128x32]*h^T + Wih[128x32]*x^T + bias, split-bf16.
// D layout (m89): col=lane&15 (sample), row=4q+r (q=lane>>4) -> lane locally
// holds i,f,g,o of units {4q+r, 16+4q+r} for its sample; that IS the next
// step's B-frag (k elems {4q+j} u {16+4q+j}) -> recurrence stays in regs.
__global__ __launch_bounds__(64, 1) void lstm_mfma_kernel(
    const unsigned short* __restrict__ seqh, const unsigned short* __restrict__ seql,
    const float* __restrict__ wih, const float* __restrict__ whh,
    const float* __restrict__ bih, const float* __restrict__ bhh,
    float* __restrict__ feats)
{
    const int s0   = blockIdx.x * 16;
    const int br   = blockIdx.y;
    const int lane = threadIdx.x;
    const int c    = lane & 15;   // sample col
    const int q    = lane >> 4;

    __shared__ f32x4 bias_lds[8][64];

    // ---- bias frags (D layout: gate = 16n + 4q + r) ----
    #pragma unroll
    for (int n = 0; n < 8; ++n) {
        f32x4 b;
        #pragma unroll
        for (int r = 0; r < 4; ++r) {
            int g = 16 * n + 4 * q + r;
            b[r] = bih[br * 128 + g] + bhh[br * 128 + g];
        }
        bias_lds[n][lane] = b;
    }

    // ---- weight A-frags: row = c (gate 16n+c), k elems {4q+j} u {16+4q+j} ----
    b16x8 wihhi[8], wihlo[8], whhhi[8], whhlo[8];
    #pragma unroll
    for (int n = 0; n < 8; ++n) {
        const int gr = 16 * n + c;
        const float* pi = wih + (size_t)br * 4096 + (size_t)gr * 32;
        const float* ph = whh + (size_t)br * 4096 + (size_t)gr * 32;
        v4f ia = *(const v4f*)(pi + 4 * q);
        v4f ib = *(const v4f*)(pi + 16 + 4 * q);
        v4f ha = *(const v4f*)(ph + 4 * q);
        v4f hb = *(const v4f*)(ph + 16 + 4 * q);
        #pragma unroll
        for (int j = 0; j < 4; ++j) {
            __bf16 t;
            t = (__bf16)ia[j]; wihhi[n][j]     = t; wihlo[n][j]     = (__bf16)(ia[j] - (float)t);
            t = (__bf16)ib[j]; wihhi[n][4 + j] = t; wihlo[n][4 + j] = (__bf16)(ib[j] - (float)t);
            t = (__bf16)ha[j]; whhhi[n][j]     = t; whhlo[n][j]     = (__bf16)(ha[j] - (float)t);
            t = (__bf16)hb[j]; whhhi[n][4 + j] = t; whhlo[n][4 + j] = (__bf16)(hb[j] - (float)t);
        }
    }

    // ---- state ----
    b16x8 bhh_f, bhl_f;
    #pragma unroll
    for (int j = 0; j < 8; ++j) { bhh_f[j] = (__bf16)0.f; bhl_f[j] = (__bf16)0.f; }
    float cst[2][4];
    #pragma unroll
    for (int hh = 0; hh < 2; ++hh)
        #pragma unroll
        for (int r = 0; r < 4; ++r) cst[hh][r] = 0.f;

    __syncthreads();

    // x frags: 16B contiguous per plane thanks to K1's swizzled layout
    size_t rowe = (((size_t)br * 512 + 0) * 2048 + s0 + c) * 32 + (size_t)q * 8;
    b16x8 bxh = *reinterpret_cast<const b16x8*>(seqh + rowe);
    b16x8 bxl = *reinterpret_cast<const b16x8*>(seql + rowe);

    #pragma unroll 1
    for (int t = 0; t < TSTEPS; ++t) {
        b16x8 nxh = bxh, nxl = bxl;
        if (t < TSTEPS - 1) {
            size_t re = (((size_t)br * 512 + (t + 1)) * 2048 + s0 + c) * 32 + (size_t)q * 8;
            nxh = *reinterpret_cast<const b16x8*>(seqh + re);
            nxl = *reinterpret_cast<const b16x8*>(seql + re);
        }

        f32x4 acc[8];
        #pragma unroll
        for (int n = 0; n < 8; ++n) acc[n] = bias_lds[n][lane];
        #pragma unroll
        for (int n = 0; n < 8; ++n) {
            acc[n] = __builtin_amdgcn_mfma_f32_16x16x32_bf16(whhhi[n], bhh_f, acc[n], 0, 0, 0);
            acc[n] = __builtin_amdgcn_mfma_f32_16x16x32_bf16(whhhi[n], bhl_f, acc[n], 0, 0, 0);
            acc[n] = __builtin_amdgcn_mfma_f32_16x16x32_bf16(whhlo[n], bhh_f, acc[n], 0, 0, 0);
            acc[n] = __builtin_amdgcn_mfma_f32_16x16x32_bf16(wihhi[n], bxh,   acc[n], 0, 0, 0);
            acc[n] = __builtin_amdgcn_mfma_f32_16x16x32_bf16(wihhi[n], bxl,   acc[n], 0, 0, 0);
            acc[n] = __builtin_amdgcn_mfma_f32_16x16x32_bf16(wihlo[n], bxh,   acc[n], 0, 0, 0);
        }

        // activations + cell update (lane-local units {4q+r, 16+4q+r})
        #pragma unroll
        for (int hh = 0; hh < 2; ++hh) {
            #pragma unroll
            for (int r = 0; r < 4; ++r) {
                float gi = acc[0 + hh][r];
                float gf = acc[2 + hh][r];
                float gg = acc[4 + hh][r];
                float go = acc[6 + hh][r];
                float si = sigf(gi);
                float sf = sigf(gf);
                float tg = tanhfast(gg);
                float so = sigf(go);
                float cc = fmaf(sf, cst[hh][r], si * tg);
                cst[hh][r] = cc;
                float hv = so * tanhfast(cc);
                __bf16 hb2 = (__bf16)hv;
                bhh_f[hh * 4 + r] = hb2;
                bhl_f[hh * 4 + r] = (__bf16)(hv - (float)hb2);
                if (t == TSTEPS - 1)
                    feats[((size_t)br * BATCH + s0 + c) * 32 + 16 * hh + 4 * q + r] = hv;
            }
        }
        bxh = nxh; bxl = nxl;
    }
}

// ============ fallback: R7 monolithic branch kernel ========================
__global__ __launch_bounds__(64, 2) void branch_fallback(
    const float* __restrict__ x0, const float* __restrict__ x1,
    const float* __restrict__ x2, const float* __restrict__ x3,
    const float* __restrict__ c1w, const float* __restrict__ c1b,
    const float* __restrict__ c2w, const float* __restrict__ c2b,
    const float* __restrict__ wih, const float* __restrict__ whh,
    const float* __restrict__ bih, const float* __restrict__ bhh,
    float* __restrict__ feats)
{
    const int s    = blockIdx.x;
    const int br   = blockIdx.y;
    const int lane = threadIdx.x;
    const float* xg = (br == 0) ? x0 : (br == 1) ? x1 : (br == 2) ? x2 : x3;

    __shared__ float xs_c[70];
    __shared__ float p1buf[34][16];
    __shared__ float seqb[CH][32];
    __shared__ float hb[2][32];

    const int ci = lane & 15;
    const int co = lane & 31;
    const int hf = lane >> 5;

    const float bs0 = bih[br * 128 + lane]      + bhh[br * 128 + lane];
    const float bs1 = bih[br * 128 + lane + 64] + bhh[br * 128 + lane + 64];

    if (lane < 32) hb[0][lane] = 0.f;
    float c_state = 0.f;

    #pragma unroll 1
    for (int chk = 0; chk < NCHUNK; ++chk) {
        const int tc0 = chk * CH;
        {
            int g = 4 * tc0 - 3 + lane;
            xs_c[lane] = ((unsigned)g < (unsigned)LSIG) ? xg[(size_t)s * LSIG + g] : 0.f;
            if (lane < 6) {
                int g2 = 4 * tc0 + 61 + lane;
                xs_c[64 + lane] = ((unsigned)g2 < (unsigned)LSIG) ? xg[(size_t)s * LSIG + g2] : 0.f;
            }
        }
        const float* pc1 = c1w + br * 48 + ci * 3;  asm volatile("" : "+v"(pc1));
        const float w10 = pc1[0], w11 = pc1[1], w12 = pc1[2];
        const float* pb1 = c1b + br * 16 + ci;      asm volatile("" : "+v"(pb1));
        const float b1v = pb1[0];
        const float* pc2 = c2w + br * 1536 + co * 48 + hf * 24;
        asm volatile("" : "+v"(pc2));
        float wt[24];
        #pragma unroll
        for (int i = 0; i < 6; ++i) ((v4f*)wt)[i] = ((const v4f*)pc2)[i];
        v4f w2p[3][2];
        #pragma unroll
        for (int k = 0; k < 3; ++k)
            #pragma unroll
            for (int h2 = 0; h2 < 2; ++h2)
                w2p[k][h2] = (v4f){ wt[(h2 * 4 + 0) * 3 + k], wt[(h2 * 4 + 1) * 3 + k],
                                    wt[(h2 * 4 + 2) * 3 + k], wt[(h2 * 4 + 3) * 3 + k] };
        const float* pb2 = c2b + br * 32 + co;      asm volatile("" : "+v"(pb2));
        const float b2v = pb2[0];
        __syncthreads();
        #pragma unroll 1
        for (int it = 0; it < 9; ++it) {
            int idx = it * 64 + lane;
            if (idx < 34 * 16) {
                int pl = idx >> 4;
                float xa = xs_c[2 * pl + 0], xb = xs_c[2 * pl + 1];
                float xc = xs_c[2 * pl + 2], xd = xs_c[2 * pl + 3];
                float a0 = fmaf(xc, w12, fmaf(xb, w11, fmaf(xa, w10, b1v)));
                float a1 = fmaf(xd, w12, fmaf(xc, w11, fmaf(xb, w10, b1v)));
                float v = fmaxf(fmaxf(a0, a1), 0.f);
                int p1g = 2 * tc0 - 1 + pl;
                v = ((unsigned)p1g < (unsigned)(LSIG / 2)) ? v : 0.f;
                p1buf[pl][idx & 15] = v;
            }
        }
        __syncthreads();
        {
            const v4f* pbase = (const v4f*)&p1buf[0][0];
            const int h2o = hf * 2;
            v4f r0a = pbase[0 * 4 + h2o], r0b = pbase[0 * 4 + h2o + 1];
            v4f r1a = pbase[1 * 4 + h2o], r1b = pbase[1 * 4 + h2o + 1];
            v4f r2a = pbase[2 * 4 + h2o], r2b = pbase[2 * 4 + h2o + 1];
            v4f r3a = pbase[3 * 4 + h2o], r3b = pbase[3 * 4 + h2o + 1];
            #pragma unroll 1
            for (int tl = 0; tl < CH; ++tl) {
                v2f aA = {0.f, 0.f}, aB = {0.f, 0.f};
                asm("v_pk_fma_f32 %0, %1, %2, %0" : "+v"(aA) : "v"(r0a.xy), "v"(w2p[0][0].xy));
                asm("v_pk_fma_f32 %0, %1, %2, %0" : "+v"(aA) : "v"(r0a.zw), "v"(w2p[0][0].zw));
                asm("v_pk_fma_f32 %0, %1, %2, %0" : "+v"(aA) : "v"(r0b.xy), "v"(w2p[0][1].xy));
                asm("v_pk_fma_f32 %0, %1, %2, %0" : "+v"(aA) : "v"(r0b.zw), "v"(w2p[0][1].zw));
                asm("v_pk_fma_f32 %0, %1, %2, %0" : "+v"(aA) : "v"(r1a.xy), "v"(w2p[1][0].xy));
                asm("v_pk_fma_f32 %0, %1, %2, %0" : "+v"(aA) : "v"(r1a.zw), "v"(w2p[1][0].zw));
                asm("v_pk_fma_f32 %0, %1, %2, %0" : "+v"(aA) : "v"(r1b.xy), "v"(w2p[1][1].xy));
                asm("v_pk_fma_f32 %0, %1, %2, %0" : "+v"(aA) : "v"(r1b.zw), "v"(w2p[1][1].zw));
                asm("v_pk_fma_f32 %0, %1, %2, %0" : "+v"(aA) : "v"(r2a.xy), "v"(w2p[2][0].xy));
                asm("v_pk_fma_f32 %0, %1, %2, %0" : "+v"(aA) : "v"(r2a.zw), "v"(w2p[2][0].zw));
                asm("v_pk_fma_f32 %0, %1, %2, %0" : "+v"(aA) : "v"(r2b.xy), "v"(w2p[2][1].xy));
                asm("v_pk_fma_f32 %0, %1, %2, %0" : "+v"(aA) : "v"(r2b.zw), "v"(w2p[2][1].zw));
                asm("v_pk_fma_f32 %0, %1, %2, %0" : "+v"(aB) : "v"(r1a.xy), "v"(w2p[0][0].xy));
                asm("v_pk_fma_f32 %0, %1, %2, %0" : "+v"(aB) : "v"(r1a.zw), "v"(w2p[0][0].zw));
                asm("v_pk_fma_f32 %0, %1, %2, %0" : "+v"(aB) : "v"(r1b.xy), "v"(w2p[0][1].xy));
                asm("v_pk_fma_f32 %0, %1, %2, %0" : "+v"(aB) : "v"(r1b.zw), "v"(w2p[0][1].zw));
                asm("v_pk_fma_f32 %0, %1, %2, %0" : "+v"(aB) : "v"(r2a.xy), "v"(w2p[1][0].xy));
                asm("v_pk_fma_f32 %0, %1, %2, %0" : "+v"(aB) : "v"(r2a.zw), "v"(w2p[1][0].zw));
                asm("v_pk_fma_f32 %0, %1, %2, %0" : "+v"(aB) : "v"(r2b.xy), "v"(w2p[1][1].xy));
                asm("v_pk_fma_f32 %0, %1, %2, %0" : "+v"(aB) : "v"(r2b.zw), "v"(w2p[1][1].zw));
                asm("v_pk_fma_f32 %0, %1, %2, %0" : "+v"(aB) : "v"(r3a.xy), "v"(w2p[2][0].xy));
                asm("v_pk_fma_f32 %0, %1, %2, %0" : "+v"(aB) : "v"(r3a.zw), "v"(w2p[2][0].zw));
                asm("v_pk_fma_f32 %0, %1, %2, %0" : "+v"(aB) : "v"(r3b.xy), "v"(w2p[2][1].xy));
                asm("v_pk_fma_f32 %0, %1, %2, %0" : "+v"(aB) : "v"(r3b.zw), "v"(w2p[2][1].zw));
                float sA = aA.x + aA.y, sB = aB.x + aB.y;
                sA += __shfl_xor(sA, 32);
                sB += __shfl_xor(sB, 32);
                if (hf == 0)
                    seqb[tl][co] = fmaxf(fmaxf(sA, sB) + b2v, 0.f);
                r0a = r2a; r0b = r2b; r1a = r3a; r1b = r3b;
                if (tl < CH - 1) {
                    r2a = pbase[(2 * tl + 4) * 4 + h2o]; r2b = pbase[(2 * tl + 4) * 4 + h2o + 1];
                    r3a = pbase[(2 * tl + 5) * 4 + h2o]; r3b = pbase[(2 * tl + 5) * 4 + h2o + 1];
                }
            }
        }
        __syncthreads();
        float gpx0[CH], gpx1[CH];
        {
            const float* pwi = wih + (size_t)br * 4096 + (size_t)lane * 32;
            asm volatile("" : "+v"(pwi));
            v4f wiA[8], wiB[8];
            #pragma unroll
            for (int j = 0; j < 8; ++j) {
                wiA[j] = ((const v4f*)pwi)[j];
                wiB[j] = ((const v4f*)(pwi + 64 * 32))[j];
            }
            #pragma unroll
            for (int tl = 0; tl < CH; ++tl) {
                const v4f* xq = (const v4f*)&seqb[tl][0];
                v2f aA = {0.f, 0.f}, aB = {0.f, 0.f};
                #pragma unroll
                for (int j = 0; j < 8; ++j) {
                    v4f xv = xq[j];
                    asm("v_pk_fma_f32 %0, %1, %2, %0" : "+v"(aA) : "v"(xv.xy), "v"(wiA[j].xy));
                    asm("v_pk_fma_f32 %0, %1, %2, %0" : "+v"(aA) : "v"(xv.zw), "v"(wiA[j].zw));
                    asm("v_pk_fma_f32 %0, %1, %2, %0" : "+v"(aB) : "v"(xv.xy), "v"(wiB[j].xy));
                    asm("v_pk_fma_f32 %0, %1, %2, %0" : "+v"(aB) : "v"(xv.zw), "v"(wiB[j].zw));
                }
                gpx0[tl] = aA.x + aA.y;
                gpx1[tl] = aB.x + aB.y;
            }
        }
        {
            const float* pwh = whh + (size_t)br * 4096 + (size_t)lane * 32;
            asm volatile("" : "+v"(pwh));
            v4f whA[8], whB[8];
            #pragma unroll
            for (int j = 0; j < 8; ++j) {
                whA[j] = ((const v4f*)pwh)[j];
                whB[j] = ((const v4f*)(pwh + 64 * 32))[j];
            }
            #pragma unroll
            for (int tl = 0; tl < CH; ++tl) {
                __syncthreads();
                const int p = (tc0 + tl) & 1;
                const v4f* hq = (const v4f*)&hb[p][0];
                v2f aA = {0.f, 0.f}, aB = {0.f, 0.f};
                #pragma unroll
                for (int j = 0; j < 8; ++j) {
                    v4f hv = hq[j];
                    asm("v_pk_fma_f32 %0, %1, %2, %0" : "+v"(aA) : "v"(hv.xy), "v"(whA[j].xy));
                    asm("v_pk_fma_f32 %0, %1, %2, %0" : "+v"(aA) : "v"(hv.zw), "v"(whA[j].zw));
                    asm("v_pk_fma_f32 %0, %1, %2, %0" : "+v"(aB) : "v"(hv.xy), "v"(whB[j].xy));
                    asm("v_pk_fma_f32 %0, %1, %2, %0" : "+v"(aB) : "v"(hv.zw), "v"(whB[j].zw));
                }
                float g0 = bs0 + gpx0[tl] + aA.x + aA.y;
                float g1 = bs1 + gpx1[tl] + aB.x + aB.y;
                float a0 = sigf(g0);
                float earg = (lane < 32) ? 2.f * g1 : -g1;
                float e1 = __expf(fminf(earg, 80.f));
                float num = (lane < 32) ? e1 - 1.f : 1.f;
                float a1 = __fdividef(num, e1 + 1.f);
                float fa = __shfl_xor(a0, 32);
                float oa = __shfl_xor(a1, 32);
                if (lane < 32) {
                    c_state = fmaf(fa, c_state, a0 * a1);
                    hb[p ^ 1][lane] = oa * tanhfast(c_state);
                }
            }
        }
    }
    __syncthreads();
    if (lane < 32)
        feats[((size_t)br * BATCH + s) * 32 + lane] = hb[0][lane];
}

// ---------------- tail: bottleneck + 8-qubit statevector + classifier -------

__device__ __forceinline__ void apply1q(float2* psi, int lane, int q,
                                        float2 g00, float2 g01,
                                        float2 g10, float2 g11)
{
    const int shift = 7 - q;
    const int right = 1 << shift;
    #pragma unroll
    for (int pp = 0; pp < 2; ++pp) {
        int p  = lane + 64 * pp;
        int l  = p >> shift;
        int r  = p & (right - 1);
        int i0 = (l << (shift + 1)) + r;
        int i1 = i0 + right;
        float2 a = psi[i0], b = psi[i1];
        float2 n0 = make_float2(g00.x * a.x - g00.y * a.y + g01.x * b.x - g01.y * b.y,
                                g00.x * a.y + g00.y * a.x + g01.x * b.y + g01.y * b.x);
        float2 n1 = make_float2(g10.x * a.x - g10.y * a.y + g11.x * b.x - g11.y * b.y,
                                g10.x * a.y + g10.y * a.x + g11.x * b.y + g11.y * b.x);
        psi[i0] = n0;
        psi[i1] = n1;
    }
    __syncthreads();
}

__global__ __launch_bounds__(64) void tail_kernel(
    const float* __restrict__ feats, const float* __restrict__ bw,
    const float* __restrict__ bb, const float* __restrict__ qw,
    const float* __restrict__ cw, const float* __restrict__ cb,
    float* __restrict__ out)
{
    const int s    = blockIdx.x;
    const int lane = threadIdx.x;

    __shared__ float comb[128];
    __shared__ float2 psi[256];
    __shared__ float ang[8];

    comb[lane]      = feats[(size_t)(lane >> 5) * (BATCH * 32) + (size_t)s * 32 + (lane & 31)];
    comb[lane + 64] = feats[(size_t)((lane + 64) >> 5) * (BATCH * 32) + (size_t)s * 32 + (lane & 31)];
    __syncthreads();

    {
        int q = lane >> 3, k0 = lane & 7;
        float p = 0.f;
        #pragma unroll
        for (int i = 0; i < 16; ++i) {
            int k = k0 + 8 * i;
            p = fmaf(comb[k], bw[q * 128 + k], p);
        }
        p += __shfl_xor(p, 4);
        p += __shfl_xor(p, 2);
        p += __shfl_xor(p, 1);
        if (k0 == 0) ang[q] = tanhf(p + bb[q]);
    }
    #pragma unroll
    for (int r = 0; r < 4; ++r) {
        int idx = lane + 64 * r;
        psi[idx] = make_float2(idx == 0 ? 1.f : 0.f, 0.f);
    }
    __syncthreads();

    const float PI_F = 3.14159265358979323846f;

    for (int q = 0; q < 8; ++q) {
        float half = ang[q] * PI_F * 0.5f;
        float cv = cosf(half), sv = sinf(half);
        apply1q(psi, lane, q,
                make_float2(cv, 0.f), make_float2(0.f, -sv),
                make_float2(0.f, -sv), make_float2(cv, 0.f));
    }

    for (int l = 0; l < 3; ++l) {
        for (int q = 0; q < 8; ++q) {
            float phi = qw[(l * 8 + q) * 3 + 0];
            float th  = qw[(l * 8 + q) * 3 + 1];
            float om  = qw[(l * 8 + q) * 3 + 2];
            float ct = cosf(0.5f * th), st = sinf(0.5f * th);
            float A = 0.5f * (phi + om), D = 0.5f * (phi - om);
            float cA = cosf(A), sA = sinf(A), cD = cosf(D), sD = sinf(D);
            apply1q(psi, lane, q,
                    make_float2(ct * cA, -ct * sA), make_float2(-st * cD, -st * sD),
                    make_float2(st * cD, -st * sD), make_float2(ct * cA,  ct * sA));
        }
        int stride = l + 1;
        for (int q = 0; q + stride < 8; ++q) {
            int cbit = 1 << (7 - q);
            int tbit = 1 << (7 - (q + stride));
            #pragma unroll
            for (int r = 0; r < 4; ++r) {
                int idx = lane + 64 * r;
                if ((idx & cbit) && !(idx & tbit)) {
                    int j = idx | tbit;
                    float2 tmp = psi[idx];
                    psi[idx] = psi[j];
                    psi[j] = tmp;
                }
            }
            __syncthreads();
        }
    }

    float z[8];
    #pragma unroll
    for (int q = 0; q < 8; ++q) z[q] = 0.f;
    #pragma unroll
    for (int r = 0; r < 4; ++r) {
        int idx = lane + 64 * r;
        float2 a = psi[idx];
        float pr = a.x * a.x + a.y * a.y;
        #pragma unroll
        for (int q = 0; q < 8; ++q)
            z[q] += (idx & (1 << (7 - q))) ? -pr : pr;
    }
    #pragma unroll
    for (int q = 0; q < 8; ++q) {
        #pragma unroll
        for (int off = 32; off; off >>= 1) z[q] += __shfl_xor(z[q], off);
    }
    if (lane == 0) {
        #pragma unroll
        for (int c = 0; c < 3; ++c) {
            float acc = cb[c];
            #pragma unroll
            for (int q = 0; q < 8; ++q) acc = fmaf(z[q], cw[c * 8 + q], acc);
            out[s * 3 + c] = acc;
        }
    }
}

extern "C" void kernel_launch(void* const* d_in, const int* in_sizes, int n_in,
                              void* d_out, int out_size, void* d_ws, size_t ws_size,
                              hipStream_t stream)
{
    (void)in_sizes; (void)n_in; (void)out_size;
    const float* x0  = (const float*)d_in[0];
    const float* x1  = (const float*)d_in[1];
    const float* x2  = (const float*)d_in[2];
    const float* x3  = (const float*)d_in[3];
    const float* c1w = (const float*)d_in[4];
    const float* c1b = (const float*)d_in[5];
    const float* c2w = (const float*)d_in[6];
    const float* c2b = (const float*)d_in[7];
    const float* wih = (const float*)d_in[8];
    const float* whh = (const float*)d_in[9];
    const float* bih = (const float*)d_in[10];
    const float* bhh = (const float*)d_in[11];
    const float* bw  = (const float*)d_in[12];
    const float* bb  = (const float*)d_in[13];
    const float* qw  = (const float*)d_in[14];
    const float* cw  = (const float*)d_in[15];
    const float* cb  = (const float*)d_in[16];

    if (ws_size >= WS_NEED) {
        unsigned short* seqh = (unsigned short*)d_ws;
        unsigned short* seql = seqh + SEQ_ELEMS;
        float* feats = (float*)((char*)d_ws + 2ULL * SEQ_ELEMS * 2ULL);
        frontend_kernel<<<dim3(BATCH, 16), 64, 0, stream>>>(
            x0, x1, x2, x3, c1w, c1b, c2w, c2b, seqh, seql);
        lstm_mfma_kernel<<<dim3(BATCH / 16, 4), 64, 0, stream>>>(
            seqh, seql, wih, whh, bih, bhh, feats);
        tail_kernel<<<BATCH, 64, 0, stream>>>(
            feats, bw, bb, qw, cw, cb, (float*)d_out);
    } else {
        float* feats = (float*)d_ws;
        branch_fallback<<<dim3(BATCH, 4), 64, 0, stream>>>(
            x0, x1, x2, x3, c1w, c1b, c2w, c2b, wih, whh, bih, bhh, feats);
        tail_kernel<<<BATCH, 64, 0, stream>>>(
            feats, bw, bb, qw, cw, cb, (float*)d_out);
    }
}

// Round 12
// 1489.586 us; speedup vs baseline: 7.4999x; 1.4804x over previous
//
#include <hip/hip_runtime.h>
#include <hip/hip_bf16.h>

#define BATCH 2048
#define LSIG 2048
#define TSTEPS 512
#define CH 16
#define NCHUNK (TSTEPS / CH)

typedef float v2f __attribute__((ext_vector_type(2)));
typedef float v4f __attribute__((ext_vector_type(4)));
typedef __bf16 b16x8 __attribute__((ext_vector_type(8)));
typedef float f32x4 __attribute__((ext_vector_type(4)));

#define PKFMA(d, a, b) asm("v_pk_fma_f32 %0, %1, %2, %0" : "+v"(d) : "v"(a), "v"(b))

__device__ __forceinline__ float sigf(float x) {
    return __fdividef(1.f, 1.f + __expf(-x));
}
__device__ __forceinline__ float tanhfast(float x) {
    return 1.f - __fdividef(2.f, __expf(2.f * x) + 1.f);
}
__device__ __forceinline__ unsigned short bf16rne(float f) {
    unsigned u = __float_as_uint(f);
    return (unsigned short)((u + 0x7FFFu + ((u >> 16) & 1u)) >> 16);
}
// swizzled channel position: K2 lane q reads 16B-contiguous frag halves
// frag elems j0..3 = ch {4q+j}, j4..7 = ch {16+4q+j}
__device__ __forceinline__ int swz(int co) {
    return (co < 16) ? ((co >> 2) * 8 + (co & 3))
                     : (((co >> 2) - 4) * 8 + 4 + (co & 3));
}

// ============ K1: conv front-end for ONE chunk -> seq hi/lo planes =========
// grid (BATCH, 4 * Tseg/16); blockIdx.y: br = y&3, ck = y>>2
__global__ __launch_bounds__(64) void frontend_kernel(
    const float* __restrict__ x0, const float* __restrict__ x1,
    const float* __restrict__ x2, const float* __restrict__ x3,
    const float* __restrict__ c1w, const float* __restrict__ c1b,
    const float* __restrict__ c2w, const float* __restrict__ c2b,
    unsigned short* __restrict__ seqh, unsigned short* __restrict__ seql,
    int t0, int Tseg)
{
    const int s    = blockIdx.x;
    const int br   = blockIdx.y & 3;
    const int ck   = blockIdx.y >> 2;
    const int lane = threadIdx.x;
    const float* xg = (br == 0) ? x0 : (br == 1) ? x1 : (br == 2) ? x2 : x3;

    __shared__ float xs_c[70];
    __shared__ float p1buf[34][16];

    const int ci = lane & 15;
    const int co = lane & 31;
    const int hf = lane >> 5;
    const int sp = swz(co);
    const int tc0 = t0 + ck * CH;     // global step base of this chunk
    const int lt0 = ck * CH;          // local (segment) step base

    const float w10 = c1w[br * 48 + ci * 3 + 0];
    const float w11 = c1w[br * 48 + ci * 3 + 1];
    const float w12 = c1w[br * 48 + ci * 3 + 2];
    const float b1v = c1b[br * 16 + ci];

    float wt[24];
    {
        const v4f* p = (const v4f*)(c2w + br * 1536 + co * 48 + hf * 24);
        #pragma unroll
        for (int i = 0; i < 6; ++i) ((v4f*)wt)[i] = p[i];
    }
    v4f w2p[3][2];
    #pragma unroll
    for (int k = 0; k < 3; ++k)
        #pragma unroll
        for (int h2 = 0; h2 < 2; ++h2)
            w2p[k][h2] = (v4f){ wt[(h2 * 4 + 0) * 3 + k], wt[(h2 * 4 + 1) * 3 + k],
                                wt[(h2 * 4 + 2) * 3 + k], wt[(h2 * 4 + 3) * 3 + k] };
    const float b2v = c2b[br * 32 + co];

    {
        int g = 4 * tc0 - 3 + lane;
        xs_c[lane] = ((unsigned)g < (unsigned)LSIG) ? xg[(size_t)s * LSIG + g] : 0.f;
        if (lane < 6) {
            int g2 = 4 * tc0 + 61 + lane;
            xs_c[64 + lane] = ((unsigned)g2 < (unsigned)LSIG) ? xg[(size_t)s * LSIG + g2] : 0.f;
        }
    }
    __syncthreads();

    // phase A
    #pragma unroll 1
    for (int it = 0; it < 9; ++it) {
        int idx = it * 64 + lane;
        if (idx < 34 * 16) {
            int pl = idx >> 4;
            float xa = xs_c[2 * pl + 0], xb = xs_c[2 * pl + 1];
            float xc = xs_c[2 * pl + 2], xd = xs_c[2 * pl + 3];
            float a0 = fmaf(xc, w12, fmaf(xb, w11, fmaf(xa, w10, b1v)));
            float a1 = fmaf(xd, w12, fmaf(xc, w11, fmaf(xb, w10, b1v)));
            float v = fmaxf(fmaxf(a0, a1), 0.f);
            int p1g = 2 * tc0 - 1 + pl;
            v = ((unsigned)p1g < (unsigned)(LSIG / 2)) ? v : 0.f;
            p1buf[pl][idx & 15] = v;
        }
    }
    __syncthreads();

    // phase B -> seq planes (swizzled channel layout, local-t indexing)
    {
        const v4f* pbase = (const v4f*)&p1buf[0][0];
        const int h2o = hf * 2;
        v4f r0a = pbase[0 * 4 + h2o], r0b = pbase[0 * 4 + h2o + 1];
        v4f r1a = pbase[1 * 4 + h2o], r1b = pbase[1 * 4 + h2o + 1];
        v4f r2a = pbase[2 * 4 + h2o], r2b = pbase[2 * 4 + h2o + 1];
        v4f r3a = pbase[3 * 4 + h2o], r3b = pbase[3 * 4 + h2o + 1];
        #pragma unroll 1
        for (int tl = 0; tl < CH; ++tl) {
            v2f aA = {0.f, 0.f}, aB = {0.f, 0.f};
            PKFMA(aA, r0a.xy, w2p[0][0].xy); PKFMA(aA, r0a.zw, w2p[0][0].zw);
            PKFMA(aA, r0b.xy, w2p[0][1].xy); PKFMA(aA, r0b.zw, w2p[0][1].zw);
            PKFMA(aA, r1a.xy, w2p[1][0].xy); PKFMA(aA, r1a.zw, w2p[1][0].zw);
            PKFMA(aA, r1b.xy, w2p[1][1].xy); PKFMA(aA, r1b.zw, w2p[1][1].zw);
            PKFMA(aA, r2a.xy, w2p[2][0].xy); PKFMA(aA, r2a.zw, w2p[2][0].zw);
            PKFMA(aA, r2b.xy, w2p[2][1].xy); PKFMA(aA, r2b.zw, w2p[2][1].zw);
            PKFMA(aB, r1a.xy, w2p[0][0].xy); PKFMA(aB, r1a.zw, w2p[0][0].zw);
            PKFMA(aB, r1b.xy, w2p[0][1].xy); PKFMA(aB, r1b.zw, w2p[0][1].zw);
            PKFMA(aB, r2a.xy, w2p[1][0].xy); PKFMA(aB, r2a.zw, w2p[1][0].zw);
            PKFMA(aB, r2b.xy, w2p[1][1].xy); PKFMA(aB, r2b.zw, w2p[1][1].zw);
            PKFMA(aB, r3a.xy, w2p[2][0].xy); PKFMA(aB, r3a.zw, w2p[2][0].zw);
            PKFMA(aB, r3b.xy, w2p[2][1].xy); PKFMA(aB, r3b.zw, w2p[2][1].zw);
            float sA = aA.x + aA.y, sB = aB.x + aB.y;
            sA += __shfl_xor(sA, 32);
            sB += __shfl_xor(sB, 32);
            float sv = fmaxf(fmaxf(sA, sB) + b2v, 0.f);
            unsigned short hb = bf16rne(sv);
            float hif = __uint_as_float(((unsigned)hb) << 16);
            unsigned short lb = bf16rne(sv - hif);
            size_t off = (((size_t)br * Tseg + (lt0 + tl)) * 2048 + s) * 32 + sp;
            if (hf == 0) seqh[off] = hb;
            else         seql[off] = lb;
            r0a = r2a; r0b = r2b; r1a = r3a; r1b = r3b;
            if (tl < CH - 1) {
                r2a = pbase[(2 * tl + 4) * 4 + h2o]; r2b = pbase[(2 * tl + 4) * 4 + h2o + 1];
                r3a = pbase[(2 * tl + 5) * 4 + h2o]; r3b = pbase[(2 * tl + 5) * 4 + h2o + 1];
            }
        }
    }
}

// ============ K2: MFMA LSTM, 16 samples/wave, segmented with state =========
// D[gates x samples]: col=lane&15 (sample), row=4q+r -> lane holds i,f,g,o of
// units {4q+r, 16+4q+r}; that IS the next step's B-frag (k={4q+j}u{16+4q+j}).
// state layout: [br][sample][0:h,1:c][32 units] f32
__global__ __launch_bounds__(64, 1) void lstm_mfma_kernel(
    const unsigned short* __restrict__ seqh, const unsigned short* __restrict__ seql,
    const float* __restrict__ wih, const float* __restrict__ whh,
    const float* __restrict__ bih, const float* __restrict__ bhh,
    float* __restrict__ state, float* __restrict__ feats,
    int t0, int Tseg)
{
    const int s0   = blockIdx.x * 16;
    const int br   = blockIdx.y;
    const int lane = threadIdx.x;
    const int c    = lane & 15;   // sample col
    const int q    = lane >> 4;

    __shared__ f32x4 bias_lds[8][64];

    #pragma unroll
    for (int n = 0; n < 8; ++n) {
        f32x4 b;
        #pragma unroll
        for (int r = 0; r < 4; ++r) {
            int g = 16 * n + 4 * q + r;
            b[r] = bih[br * 128 + g] + bhh[br * 128 + g];
        }
        bias_lds[n][lane] = b;
    }

    // weight A-frags: row = c (gate 16n+c), k elems {4q+j} u {16+4q+j}
    b16x8 wihhi[8], wihlo[8], whhhi[8], whhlo[8];
    #pragma unroll
    for (int n = 0; n < 8; ++n) {
        const int gr = 16 * n + c;
        const float* pi = wih + (size_t)br * 4096 + (size_t)gr * 32;
        const float* ph = whh + (size_t)br * 4096 + (size_t)gr * 32;
        v4f ia = *(const v4f*)(pi + 4 * q);
        v4f ib = *(const v4f*)(pi + 16 + 4 * q);
        v4f ha = *(const v4f*)(ph + 4 * q);
        v4f hb = *(const v4f*)(ph + 16 + 4 * q);
        #pragma unroll
        for (int j = 0; j < 4; ++j) {
            __bf16 t;
            t = (__bf16)ia[j]; wihhi[n][j]     = t; wihlo[n][j]     = (__bf16)(ia[j] - (float)t);
            t = (__bf16)ib[j]; wihhi[n][4 + j] = t; wihlo[n][4 + j] = (__bf16)(ib[j] - (float)t);
            t = (__bf16)ha[j]; whhhi[n][j]     = t; whhlo[n][j]     = (__bf16)(ha[j] - (float)t);
            t = (__bf16)hb[j]; whhhi[n][4 + j] = t; whhlo[n][4 + j] = (__bf16)(hb[j] - (float)t);
        }
    }

    // state: init or restore
    b16x8 bhh_f, bhl_f;
    float cst[2][4];
    if (t0 == 0) {
        #pragma unroll
        for (int j = 0; j < 8; ++j) { bhh_f[j] = (__bf16)0.f; bhl_f[j] = (__bf16)0.f; }
        #pragma unroll
        for (int hh = 0; hh < 2; ++hh)
            #pragma unroll
            for (int r = 0; r < 4; ++r) cst[hh][r] = 0.f;
    } else {
        const float* st = state + (((size_t)br * BATCH + s0 + c) * 2) * 32;
        #pragma unroll
        for (int hh = 0; hh < 2; ++hh)
            #pragma unroll
            for (int r = 0; r < 4; ++r) {
                int u = 16 * hh + 4 * q + r;
                float hv = st[u];
                __bf16 hb2 = (__bf16)hv;
                bhh_f[hh * 4 + r] = hb2;
                bhl_f[hh * 4 + r] = (__bf16)(hv - (float)hb2);
                cst[hh][r] = st[32 + u];
            }
    }
    __syncthreads();

    size_t rowe = (((size_t)br * Tseg + 0) * 2048 + s0 + c) * 32 + (size_t)q * 8;
    b16x8 bxh = *reinterpret_cast<const b16x8*>(seqh + rowe);
    b16x8 bxl = *reinterpret_cast<const b16x8*>(seql + rowe);

    #pragma unroll 1
    for (int t = 0; t < Tseg; ++t) {
        b16x8 nxh = bxh, nxl = bxl;
        if (t < Tseg - 1) {
            size_t re = (((size_t)br * Tseg + (t + 1)) * 2048 + s0 + c) * 32 + (size_t)q * 8;
            nxh = *reinterpret_cast<const b16x8*>(seqh + re);
            nxl = *reinterpret_cast<const b16x8*>(seql + re);
        }

        f32x4 acc[8];
        #pragma unroll
        for (int n = 0; n < 8; ++n) acc[n] = bias_lds[n][lane];
        #pragma unroll
        for (int n = 0; n < 8; ++n) {
            acc[n] = __builtin_amdgcn_mfma_f32_16x16x32_bf16(whhhi[n], bhh_f, acc[n], 0, 0, 0);
            acc[n] = __builtin_amdgcn_mfma_f32_16x16x32_bf16(whhhi[n], bhl_f, acc[n], 0, 0, 0);
            acc[n] = __builtin_amdgcn_mfma_f32_16x16x32_bf16(whhlo[n], bhh_f, acc[n], 0, 0, 0);
            acc[n] = __builtin_amdgcn_mfma_f32_16x16x32_bf16(wihhi[n], bxh,   acc[n], 0, 0, 0);
            acc[n] = __builtin_amdgcn_mfma_f32_16x16x32_bf16(wihhi[n], bxl,   acc[n], 0, 0, 0);
            acc[n] = __builtin_amdgcn_mfma_f32_16x16x32_bf16(wihlo[n], bxh,   acc[n], 0, 0, 0);
        }

        const bool last = (t0 + t == TSTEPS - 1);
        #pragma unroll
        for (int hh = 0; hh < 2; ++hh) {
            #pragma unroll
            for (int r = 0; r < 4; ++r) {
                float gi = acc[0 + hh][r];
                float gf = acc[2 + hh][r];
                float gg = acc[4 + hh][r];
                float go = acc[6 + hh][r];
                float si = sigf(gi);
                float sf = sigf(gf);
                float tg = tanhfast(gg);
                float so = sigf(go);
                float cc = fmaf(sf, cst[hh][r], si * tg);
                cst[hh][r] = cc;
                float hv = so * tanhfast(cc);
                __bf16 hb2 = (__bf16)hv;
                bhh_f[hh * 4 + r] = hb2;
                bhl_f[hh * 4 + r] = (__bf16)(hv - (float)hb2);
                if (last)
                    feats[((size_t)br * BATCH + s0 + c) * 32 + 16 * hh + 4 * q + r] = hv;
            }
        }
        bxh = nxh; bxl = nxl;
    }

    // save state for next segment
    if (t0 + Tseg < TSTEPS) {
        float* st = state + (((size_t)br * BATCH + s0 + c) * 2) * 32;
        #pragma unroll
        for (int hh = 0; hh < 2; ++hh)
            #pragma unroll
            for (int r = 0; r < 4; ++r) {
                int u = 16 * hh + 4 * q + r;
                st[u]      = (float)bhh_f[hh * 4 + r] + (float)bhl_f[hh * 4 + r];
                st[32 + u] = cst[hh][r];
            }
    }
}

// ============ fallback: R7 monolithic branch kernel ========================
__global__ __launch_bounds__(64, 2) void branch_fallback(
    const float* __restrict__ x0, const float* __restrict__ x1,
    const float* __restrict__ x2, const float* __restrict__ x3,
    const float* __restrict__ c1w, const float* __restrict__ c1b,
    const float* __restrict__ c2w, const float* __restrict__ c2b,
    const float* __restrict__ wih, const float* __restrict__ whh,
    const float* __restrict__ bih, const float* __restrict__ bhh,
    float* __restrict__ feats)
{
    const int s    = blockIdx.x;
    const int br   = blockIdx.y;
    const int lane = threadIdx.x;
    const float* xg = (br == 0) ? x0 : (br == 1) ? x1 : (br == 2) ? x2 : x3;

    __shared__ float xs_c[70];
    __shared__ float p1buf[34][16];
    __shared__ float seqb[CH][32];
    __shared__ float hb[2][32];

    const int ci = lane & 15;
    const int co = lane & 31;
    const int hf = lane >> 5;

    const float bs0 = bih[br * 128 + lane]      + bhh[br * 128 + lane];
    const float bs1 = bih[br * 128 + lane + 64] + bhh[br * 128 + lane + 64];

    if (lane < 32) hb[0][lane] = 0.f;
    float c_state = 0.f;

    #pragma unroll 1
    for (int chk = 0; chk < NCHUNK; ++chk) {
        const int tc0 = chk * CH;
        {
            int g = 4 * tc0 - 3 + lane;
            xs_c[lane] = ((unsigned)g < (unsigned)LSIG) ? xg[(size_t)s * LSIG + g] : 0.f;
            if (lane < 6) {
                int g2 = 4 * tc0 + 61 + lane;
                xs_c[64 + lane] = ((unsigned)g2 < (unsigned)LSIG) ? xg[(size_t)s * LSIG + g2] : 0.f;
            }
        }
        const float* pc1 = c1w + br * 48 + ci * 3;  asm volatile("" : "+v"(pc1));
        const float w10 = pc1[0], w11 = pc1[1], w12 = pc1[2];
        const float* pb1 = c1b + br * 16 + ci;      asm volatile("" : "+v"(pb1));
        const float b1v = pb1[0];
        const float* pc2 = c2w + br * 1536 + co * 48 + hf * 24;
        asm volatile("" : "+v"(pc2));
        float wt[24];
        #pragma unroll
        for (int i = 0; i < 6; ++i) ((v4f*)wt)[i] = ((const v4f*)pc2)[i];
        v4f w2p[3][2];
        #pragma unroll
        for (int k = 0; k < 3; ++k)
            #pragma unroll
            for (int h2 = 0; h2 < 2; ++h2)
                w2p[k][h2] = (v4f){ wt[(h2 * 4 + 0) * 3 + k], wt[(h2 * 4 + 1) * 3 + k],
                                    wt[(h2 * 4 + 2) * 3 + k], wt[(h2 * 4 + 3) * 3 + k] };
        const float* pb2 = c2b + br * 32 + co;      asm volatile("" : "+v"(pb2));
        const float b2v = pb2[0];
        __syncthreads();
        #pragma unroll 1
        for (int it = 0; it < 9; ++it) {
            int idx = it * 64 + lane;
            if (idx < 34 * 16) {
                int pl = idx >> 4;
                float xa = xs_c[2 * pl + 0], xb = xs_c[2 * pl + 1];
                float xc = xs_c[2 * pl + 2], xd = xs_c[2 * pl + 3];
                float a0 = fmaf(xc, w12, fmaf(xb, w11, fmaf(xa, w10, b1v)));
                float a1 = fmaf(xd, w12, fmaf(xc, w11, fmaf(xb, w10, b1v)));
                float v = fmaxf(fmaxf(a0, a1), 0.f);
                int p1g = 2 * tc0 - 1 + pl;
                v = ((unsigned)p1g < (unsigned)(LSIG / 2)) ? v : 0.f;
                p1buf[pl][idx & 15] = v;
            }
        }
        __syncthreads();
        {
            const v4f* pbase = (const v4f*)&p1buf[0][0];
            const int h2o = hf * 2;
            v4f r0a = pbase[0 * 4 + h2o], r0b = pbase[0 * 4 + h2o + 1];
            v4f r1a = pbase[1 * 4 + h2o], r1b = pbase[1 * 4 + h2o + 1];
            v4f r2a = pbase[2 * 4 + h2o], r2b = pbase[2 * 4 + h2o + 1];
            v4f r3a = pbase[3 * 4 + h2o], r3b = pbase[3 * 4 + h2o + 1];
            #pragma unroll 1
            for (int tl = 0; tl < CH; ++tl) {
                v2f aA = {0.f, 0.f}, aB = {0.f, 0.f};
                PKFMA(aA, r0a.xy, w2p[0][0].xy); PKFMA(aA, r0a.zw, w2p[0][0].zw);
                PKFMA(aA, r0b.xy, w2p[0][1].xy); PKFMA(aA, r0b.zw, w2p[0][1].zw);
                PKFMA(aA, r1a.xy, w2p[1][0].xy); PKFMA(aA, r1a.zw, w2p[1][0].zw);
                PKFMA(aA, r1b.xy, w2p[1][1].xy); PKFMA(aA, r1b.zw, w2p[1][1].zw);
                PKFMA(aA, r2a.xy, w2p[2][0].xy); PKFMA(aA, r2a.zw, w2p[2][0].zw);
                PKFMA(aA, r2b.xy, w2p[2][1].xy); PKFMA(aA, r2b.zw, w2p[2][1].zw);
                PKFMA(aB, r1a.xy, w2p[0][0].xy); PKFMA(aB, r1a.zw, w2p[0][0].zw);
                PKFMA(aB, r1b.xy, w2p[0][1].xy); PKFMA(aB, r1b.zw, w2p[0][1].zw);
                PKFMA(aB, r2a.xy, w2p[1][0].xy); PKFMA(aB, r2a.zw, w2p[1][0].zw);
                PKFMA(aB, r2b.xy, w2p[1][1].xy); PKFMA(aB, r2b.zw, w2p[1][1].zw);
                PKFMA(aB, r3a.xy, w2p[2][0].xy); PKFMA(aB, r3a.zw, w2p[2][0].zw);
                PKFMA(aB, r3b.xy, w2p[2][1].xy); PKFMA(aB, r3b.zw, w2p[2][1].zw);
                float sA = aA.x + aA.y, sB = aB.x + aB.y;
                sA += __shfl_xor(sA, 32);
                sB += __shfl_xor(sB, 32);
                if (hf == 0)
                    seqb[tl][co] = fmaxf(fmaxf(sA, sB) + b2v, 0.f);
                r0a = r2a; r0b = r2b; r1a = r3a; r1b = r3b;
                if (tl < CH - 1) {
                    r2a = pbase[(2 * tl + 4) * 4 + h2o]; r2b = pbase[(2 * tl + 4) * 4 + h2o + 1];
                    r3a = pbase[(2 * tl + 5) * 4 + h2o]; r3b = pbase[(2 * tl + 5) * 4 + h2o + 1];
                }
            }
        }
        __syncthreads();
        float gpx0[CH], gpx1[CH];
        {
            const float* pwi = wih + (size_t)br * 4096 + (size_t)lane * 32;
            asm volatile("" : "+v"(pwi));
            v4f wiA[8], wiB[8];
            #pragma unroll
            for (int j = 0; j < 8; ++j) {
                wiA[j] = ((const v4f*)pwi)[j];
                wiB[j] = ((const v4f*)(pwi + 64 * 32))[j];
            }
            #pragma unroll
            for (int tl = 0; tl < CH; ++tl) {
                const v4f* xq = (const v4f*)&seqb[tl][0];
                v2f aA = {0.f, 0.f}, aB = {0.f, 0.f};
                #pragma unroll
                for (int j = 0; j < 8; ++j) {
                    v4f xv = xq[j];
                    PKFMA(aA, xv.xy, wiA[j].xy); PKFMA(aA, xv.zw, wiA[j].zw);
                    PKFMA(aB, xv.xy, wiB[j].xy); PKFMA(aB, xv.zw, wiB[j].zw);
                }
                gpx0[tl] = aA.x + aA.y;
                gpx1[tl] = aB.x + aB.y;
            }
        }
        {
            const float* pwh = whh + (size_t)br * 4096 + (size_t)lane * 32;
            asm volatile("" : "+v"(pwh));
            v4f whA[8], whB[8];
            #pragma unroll
            for (int j = 0; j < 8; ++j) {
                whA[j] = ((const v4f*)pwh)[j];
                whB[j] = ((const v4f*)(pwh + 64 * 32))[j];
            }
            #pragma unroll
            for (int tl = 0; tl < CH; ++tl) {
                __syncthreads();
                const int p = (tc0 + tl) & 1;
                const v4f* hq = (const v4f*)&hb[p][0];
                v2f aA = {0.f, 0.f}, aB = {0.f, 0.f};
                #pragma unroll
                for (int j = 0; j < 8; ++j) {
                    v4f hv = hq[j];
                    PKFMA(aA, hv.xy, whA[j].xy); PKFMA(aA, hv.zw, whA[j].zw);
                    PKFMA(aB, hv.xy, whB[j].xy); PKFMA(aB, hv.zw, whB[j].zw);
                }
                float g0 = bs0 + gpx0[tl] + aA.x + aA.y;
                float g1 = bs1 + gpx1[tl] + aB.x + aB.y;
                float a0 = sigf(g0);
                float earg = (lane < 32) ? 2.f * g1 : -g1;
                float e1 = __expf(fminf(earg, 80.f));
                float num = (lane < 32) ? e1 - 1.f : 1.f;
                float a1 = __fdividef(num, e1 + 1.f);
                float fa = __shfl_xor(a0, 32);
                float oa = __shfl_xor(a1, 32);
                if (lane < 32) {
                    c_state = fmaf(fa, c_state, a0 * a1);
                    hb[p ^ 1][lane] = oa * tanhfast(c_state);
                }
            }
        }
    }
    __syncthreads();
    if (lane < 32)
        feats[((size_t)br * BATCH + s) * 32 + lane] = hb[0][lane];
}

// ---------------- tail: bottleneck + 8-qubit statevector + classifier -------

__device__ __forceinline__ void apply1q(float2* psi, int lane, int q,
                                        float2 g00, float2 g01,
                                        float2 g10, float2 g11)
{
    const int shift = 7 - q;
    const int right = 1 << shift;
    #pragma unroll
    for (int pp = 0; pp < 2; ++pp) {
        int p  = lane + 64 * pp;
        int l  = p >> shift;
        int r  = p & (right - 1);
        int i0 = (l << (shift + 1)) + r;
        int i1 = i0 + right;
        float2 a = psi[i0], b = psi[i1];
        float2 n0 = make_float2(g00.x * a.x - g00.y * a.y + g01.x * b.x - g01.y * b.y,
                                g00.x * a.y + g00.y * a.x + g01.x * b.y + g01.y * b.x);
        float2 n1 = make_float2(g10.x * a.x - g10.y * a.y + g11.x * b.x - g11.y * b.y,
                                g10.x * a.y + g10.y * a.x + g11.x * b.y + g11.y * b.x);
        psi[i0] = n0;
        psi[i1] = n1;
    }
    __syncthreads();
}

__global__ __launch_bounds__(64) void tail_kernel(
    const float* __restrict__ feats, const float* __restrict__ bw,
    const float* __restrict__ bb, const float* __restrict__ qw,
    const float* __restrict__ cw, const float* __restrict__ cb,
    float* __restrict__ out)
{
    const int s    = blockIdx.x;
    const int lane = threadIdx.x;

    __shared__ float comb[128];
    __shared__ float2 psi[256];
    __shared__ float ang[8];

    comb[lane]      = feats[(size_t)(lane >> 5) * (BATCH * 32) + (size_t)s * 32 + (lane & 31)];
    comb[lane + 64] = feats[(size_t)((lane + 64) >> 5) * (BATCH * 32) + (size_t)s * 32 + (lane & 31)];
    __syncthreads();

    {
        int q = lane >> 3, k0 = lane & 7;
        float p = 0.f;
        #pragma unroll
        for (int i = 0; i < 16; ++i) {
            int k = k0 + 8 * i;
            p = fmaf(comb[k], bw[q * 128 + k], p);
        }
        p += __shfl_xor(p, 4);
        p += __shfl_xor(p, 2);
        p += __shfl_xor(p, 1);
        if (k0 == 0) ang[q] = tanhf(p + bb[q]);
    }
    #pragma unroll
    for (int r = 0; r < 4; ++r) {
        int idx = lane + 64 * r;
        psi[idx] = make_float2(idx == 0 ? 1.f : 0.f, 0.f);
    }
    __syncthreads();

    const float PI_F = 3.14159265358979323846f;

    for (int q = 0; q < 8; ++q) {
        float half = ang[q] * PI_F * 0.5f;
        float cv = cosf(half), sv = sinf(half);
        apply1q(psi, lane, q,
                make_float2(cv, 0.f), make_float2(0.f, -sv),
                make_float2(0.f, -sv), make_float2(cv, 0.f));
    }

    for (int l = 0; l < 3; ++l) {
        for (int q = 0; q < 8; ++q) {
            float phi = qw[(l * 8 + q) * 3 + 0];
            float th  = qw[(l * 8 + q) * 3 + 1];
            float om  = qw[(l * 8 + q) * 3 + 2];
            float ct = cosf(0.5f * th), st = sinf(0.5f * th);
            float A = 0.5f * (phi + om), D = 0.5f * (phi - om);
            float cA = cosf(A), sA = sinf(A), cD = cosf(D), sD = sinf(D);
            apply1q(psi, lane, q,
                    make_float2(ct * cA, -ct * sA), make_float2(-st * cD, -st * sD),
                    make_float2(st * cD, -st * sD), make_float2(ct * cA,  ct * sA));
        }
        int stride = l + 1;
        for (int q = 0; q + stride < 8; ++q) {
            int cbit = 1 << (7 - q);
            int tbit = 1 << (7 - (q + stride));
            #pragma unroll
            for (int r = 0; r < 4; ++r) {
                int idx = lane + 64 * r;
                if ((idx & cbit) && !(idx & tbit)) {
                    int j = idx | tbit;
                    float2 tmp = psi[idx];
                    psi[idx] = psi[j];
                    psi[j] = tmp;
                }
            }
            __syncthreads();
        }
    }

    float z[8];
    #pragma unroll
    for (int q = 0; q < 8; ++q) z[q] = 0.f;
    #pragma unroll
    for (int r = 0; r < 4; ++r) {
        int idx = lane + 64 * r;
        float2 a = psi[idx];
        float pr = a.x * a.x + a.y * a.y;
        #pragma unroll
        for (int q = 0; q < 8; ++q)
            z[q] += (idx & (1 << (7 - q))) ? -pr : pr;
    }
    #pragma unroll
    for (int q = 0; q < 8; ++q) {
        #pragma unroll
        for (int off = 32; off; off >>= 1) z[q] += __shfl_xor(z[q], off);
    }
    if (lane == 0) {
        #pragma unroll
        for (int c = 0; c < 3; ++c) {
            float acc = cb[c];
            #pragma unroll
            for (int q = 0; q < 8; ++q) acc = fmaf(z[q], cw[c * 8 + q], acc);
            out[s * 3 + c] = acc;
        }
    }
}

extern "C" void kernel_launch(void* const* d_in, const int* in_sizes, int n_in,
                              void* d_out, int out_size, void* d_ws, size_t ws_size,
                              hipStream_t stream)
{
    (void)in_sizes; (void)n_in; (void)out_size;
    const float* x0  = (const float*)d_in[0];
    const float* x1  = (const float*)d_in[1];
    const float* x2  = (const float*)d_in[2];
    const float* x3  = (const float*)d_in[3];
    const float* c1w = (const float*)d_in[4];
    const float* c1b = (const float*)d_in[5];
    const float* c2w = (const float*)d_in[6];
    const float* c2b = (const float*)d_in[7];
    const float* wih = (const float*)d_in[8];
    const float* whh = (const float*)d_in[9];
    const float* bih = (const float*)d_in[10];
    const float* bhh = (const float*)d_in[11];
    const float* bw  = (const float*)d_in[12];
    const float* bb  = (const float*)d_in[13];
    const float* qw  = (const float*)d_in[14];
    const float* cw  = (const float*)d_in[15];
    const float* cb  = (const float*)d_in[16];

    const size_t state_b = 4ULL * BATCH * 64ULL * 4ULL;       // 2 MB
    const size_t feats_b = 4ULL * BATCH * 32ULL * 4ULL;       // 1 MB
    const size_t per_t   = 4ULL * 2048ULL * 32ULL * 4ULL;     // 1 MB/step (hi+lo)

    int Tseg = 0;
    for (int cand = 512; cand >= 32; cand >>= 1) {
        if ((size_t)cand * per_t + state_b + feats_b <= ws_size) { Tseg = cand; break; }
    }

    if (Tseg > 0) {
        size_t seg_elems = (size_t)Tseg * 4ULL * 2048ULL * 32ULL;
        unsigned short* seqh = (unsigned short*)d_ws;
        unsigned short* seql = seqh + seg_elems;
        float* state = (float*)((char*)d_ws + 2ULL * seg_elems * 2ULL);
        float* feats = (float*)((char*)state + state_b);

        for (int t0 = 0; t0 < TSTEPS; t0 += Tseg) {
            frontend_kernel<<<dim3(BATCH, 4 * (Tseg / CH)), 64, 0, stream>>>(
                x0, x1, x2, x3, c1w, c1b, c2w, c2b, seqh, seql, t0, Tseg);
            lstm_mfma_kernel<<<dim3(BATCH / 16, 4), 64, 0, stream>>>(
                seqh, seql, wih, whh, bih, bhh, state, feats, t0, Tseg);
        }
        tail_kernel<<<BATCH, 64, 0, stream>>>(
            feats, bw, bb, qw, cw, cb, (float*)d_out);
    } else {
        float* feats = (float*)d_ws;
        branch_fallback<<<dim3(BATCH, 4), 64, 0, stream>>>(
            x0, x1, x2, x3, c1w, c1b, c2w, c2b, wih, whh, bih, bhh, feats);
        tail_kernel<<<BATCH, 64, 0, stream>>>(
            feats, bw, bb, qw, cw, cb, (float*)d_out);
    }
}